// Round 1
// baseline (524.993 us; speedup 1.0000x reference)
//
#include <hip/hip_runtime.h>
#include <hip/hip_bf16.h>
#include <cstdint>
#include <cstddef>

// ---------------- problem constants ----------------
#define B_    8
#define Q_    2048
#define DIM_  256
#define NH    8
#define HD    32
#define NL    4
#define NP    4
#define DFF   1024
#define LEN_IN_ 13294
#define MV    (B_*LEN_IN_)     // 106352
#define MVPAD 106368           // 831*128
#define MQ    (B_*Q_)          // 16384

typedef unsigned short u16;
typedef __attribute__((ext_vector_type(8))) short short8;
typedef __attribute__((ext_vector_type(4))) float f32x4v;
typedef __attribute__((ext_vector_type(4))) unsigned short u16x4;

static __device__ __forceinline__ u16 f2bf(float f){
  union { float f; unsigned u; } x; x.f = f;
  unsigned r = x.u + 0x7fffu + ((x.u >> 16) & 1u);
  return (u16)(r >> 16);
}
static __device__ __forceinline__ float bf2f(u16 h){
  union { unsigned u; float f; } x; x.u = ((unsigned)h) << 16;
  return x.f;
}

// ---------------- generic bf16 MFMA GEMM ----------------
// C[M][N] = A[M][K] @ Bt[N][K]^T + bias ; A,Bt bf16 row-major; acc fp32.
// EPI: 0 = f32 store (+bias); 1 = bf16 store (+bias);
//      2 = f32 store (+bias + residual); 3 = bf16 store (+bias + relu)
template<int EPI>
__global__ __launch_bounds__(256)
void gemm_k(const u16* __restrict__ A, const u16* __restrict__ Bt,
            const float* __restrict__ bias, const float* __restrict__ res,
            void* __restrict__ outp, int N, int K, int Mstore)
{
  __shared__ u16 As[128*64];
  __shared__ u16 Bs[128*64];
  const int t = threadIdx.x;
  const int l = t & 63, wid = t >> 6;
  const int wm = wid >> 1, wn = wid & 1;
  const int m0 = blockIdx.x * 128, n0 = blockIdx.y * 128;

  f32x4v acc[4][4];
#pragma unroll
  for (int i = 0; i < 4; ++i)
#pragma unroll
    for (int j = 0; j < 4; ++j) acc[i][j] = 0.f;

  const int nkt = K >> 6;
  for (int kt = 0; kt < nkt; ++kt) {
    // ---- stage 128x64 bf16 tiles of A and Bt via global_load_lds (16B), source pre-swizzled
#pragma unroll
    for (int i = 0; i < 4; ++i) {
      int chunk = i * 256 + t;          // 0..1023 16B-chunks
      int row   = chunk >> 3;           // 8 chunks per 64-col row
      int c16   = chunk & 7;
      int sc    = c16 ^ (row & 7);      // inverse swizzle on SOURCE, linear LDS dest
      const u16* ga = A  + (size_t)(m0 + row) * K + kt * 64 + sc * 8;
      __builtin_amdgcn_global_load_lds((const __attribute__((address_space(1))) void*)ga,
                                       (__attribute__((address_space(3))) void*)(As + chunk * 8), 16, 0, 0);
      const u16* gb = Bt + (size_t)(n0 + row) * K + kt * 64 + sc * 8;
      __builtin_amdgcn_global_load_lds((const __attribute__((address_space(1))) void*)gb,
                                       (__attribute__((address_space(3))) void*)(Bs + chunk * 8), 16, 0, 0);
    }
    __syncthreads();
#pragma unroll
    for (int kk = 0; kk < 2; ++kk) {
      short8 af[4], bfr[4];
      const int lr  = l & 15;
      const int c   = kk * 4 + (l >> 4);
      const int swz = c ^ (lr & 7);
#pragma unroll
      for (int mi = 0; mi < 4; ++mi) {
        int r = wm * 64 + mi * 16 + lr;
        af[mi] = *reinterpret_cast<const short8*>(As + (r * 8 + swz) * 8);
      }
#pragma unroll
      for (int ni = 0; ni < 4; ++ni) {
        int r = wn * 64 + ni * 16 + lr;
        bfr[ni] = *reinterpret_cast<const short8*>(Bs + (r * 8 + swz) * 8);
      }
#pragma unroll
      for (int mi = 0; mi < 4; ++mi)
#pragma unroll
        for (int ni = 0; ni < 4; ++ni)
          acc[mi][ni] = __builtin_amdgcn_mfma_f32_16x16x32_bf16(af[mi], bfr[ni], acc[mi][ni], 0, 0, 0);
    }
    __syncthreads();
  }

  // ---- epilogue: C/D layout col = l&15, row = 4*(l>>4)+v
  const int lr4 = l >> 4;
#pragma unroll
  for (int mi = 0; mi < 4; ++mi) {
    int rowb = m0 + wm * 64 + mi * 16 + lr4 * 4;
#pragma unroll
    for (int ni = 0; ni < 4; ++ni) {
      int col = n0 + wn * 64 + ni * 16 + (l & 15);
      float bb = bias[col];
#pragma unroll
      for (int v = 0; v < 4; ++v) {
        int r = rowb + v;
        if (r < Mstore) {
          float cv = acc[mi][ni][v] + bb;
          if (EPI == 2) cv += res[(size_t)r * N + col];
          if (EPI == 3) cv = fmaxf(cv, 0.f);
          if (EPI == 0 || EPI == 2) ((float*)outp)[(size_t)r * N + col] = cv;
          else                      ((u16*)outp)[(size_t)r * N + col] = f2bf(cv);
        }
      }
    }
  }
}

// ---------------- weight transpose fp32[K][N] -> bf16[N][K] ----------------
__global__ void transpose_w(const float* __restrict__ in, u16* __restrict__ out, int K, int N)
{
  int gid = blockIdx.x * 256 + threadIdx.x;
  if (gid < K * N) {
    int n = gid / K, k = gid - n * K;
    out[gid] = f2bf(in[(size_t)k * N + n]);
  }
}

// ---------------- source fp32 -> bf16 (+ zero pad rows) ----------------
__global__ void cvt_src(const float* __restrict__ src, u16* __restrict__ dst)
{
  size_t gid = (size_t)blockIdx.x * 256 + threadIdx.x;   // per float4 group
  size_t base = gid * 4;
  const size_t nsrc = (size_t)MV * DIM_;
  u16x4 o;
  if (base < nsrc) {
    const float4 v = reinterpret_cast<const float4*>(src)[gid];
    o.x = f2bf(v.x); o.y = f2bf(v.y); o.z = f2bf(v.z); o.w = f2bf(v.w);
  } else {
    o.x = 0; o.y = 0; o.z = 0; o.w = 0;
  }
  *reinterpret_cast<u16x4*>(dst + base) = o;
}

// ---------------- LayerNorm (warp per 256-float row) -> bf16 out ----------------
template<bool ADDPOS>
__global__ __launch_bounds__(256)
void ln_k(const float* __restrict__ x, const float* __restrict__ pos,
          const float* __restrict__ g, const float* __restrict__ b, u16* __restrict__ out)
{
  const int warp = threadIdx.x >> 6, l = threadIdx.x & 63;
  const int row = blockIdx.x * 4 + warp;
  const float4 xv = reinterpret_cast<const float4*>(x + (size_t)row * 256)[l];
  float s = xv.x + xv.y + xv.z + xv.w;
#pragma unroll
  for (int o = 32; o; o >>= 1) s += __shfl_xor(s, o);
  const float mean = s * (1.f / 256.f);
  const float d0 = xv.x - mean, d1 = xv.y - mean, d2 = xv.z - mean, d3 = xv.w - mean;
  float vs = d0 * d0 + d1 * d1 + d2 * d2 + d3 * d3;
#pragma unroll
  for (int o = 32; o; o >>= 1) vs += __shfl_xor(vs, o);
  const float rs = rsqrtf(vs * (1.f / 256.f) + 1e-5f);
  const float4 gv = reinterpret_cast<const float4*>(g)[l];
  const float4 bv = reinterpret_cast<const float4*>(b)[l];
  float o0 = d0 * rs * gv.x + bv.x;
  float o1 = d1 * rs * gv.y + bv.y;
  float o2 = d2 * rs * gv.z + bv.z;
  float o3 = d3 * rs * gv.w + bv.w;
  if (ADDPOS) {
    const float4 pv = reinterpret_cast<const float4*>(pos + (size_t)row * 256)[l];
    o0 += pv.x; o1 += pv.y; o2 += pv.z; o3 += pv.w;
  }
  u16x4 ov; ov.x = f2bf(o0); ov.y = f2bf(o1); ov.z = f2bf(o2); ov.w = f2bf(o3);
  reinterpret_cast<u16x4*>(out + (size_t)row * 256)[l] = ov;
}

// ---------------- softmax over 16 (in-place) ----------------
__global__ void softmax16(float* __restrict__ a)
{
  const size_t gid = (size_t)blockIdx.x * 256 + threadIdx.x;  // one (b,q,h)
  float* p = a + gid * 16;
  float v[16];
#pragma unroll
  for (int i = 0; i < 16; ++i) v[i] = p[i];
  float m = v[0];
#pragma unroll
  for (int i = 1; i < 16; ++i) m = fmaxf(m, v[i]);
  float s = 0.f;
#pragma unroll
  for (int i = 0; i < 16; ++i) { v[i] = __expf(v[i] - m); s += v[i]; }
  const float inv = 1.f / s;
#pragma unroll
  for (int i = 0; i < 16; ++i) p[i] = v[i] * inv;
}

// ---------------- loc = ref + off/normalizer  (writes output 1) ----------------
__global__ void loc_k(const float* __restrict__ offraw, const float* __restrict__ refpt,
                      float* __restrict__ locout)
{
  const int i = blockIdx.x * 256 + threadIdx.x;   // (row,h,l,p) = B*Q*8*16
  const int p = i & 3, lv = (i >> 2) & 3, h = (i >> 4) & 7, row = i >> 7;
  const float ox = offraw[(size_t)row * 256 + h * 32 + lv * 8 + p * 2 + 0];
  const float oy = offraw[(size_t)row * 256 + h * 32 + lv * 8 + p * 2 + 1];
  const float rn = (lv == 0) ? (1.f / 100.f) : (lv == 1) ? (1.f / 50.f) : (lv == 2) ? (1.f / 25.f) : (1.f / 13.f);
  const float rx = refpt[(size_t)row * 8 + lv * 2 + 0];
  const float ry = refpt[(size_t)row * 8 + lv * 2 + 1];
  locout[(size_t)i * 2 + 0] = rx + ox * rn;
  locout[(size_t)i * 2 + 1] = ry + oy * rn;
}

// ---------------- multiscale deformable sampling ----------------
__global__ __launch_bounds__(256)
void msdeform_k(const u16* __restrict__ value, const float* __restrict__ attnw,
                const float* __restrict__ loc, u16* __restrict__ outp)
{
  const int row = blockIdx.x;            // b*Q + q
  const int t = threadIdx.x;
  const int h = t >> 5, d = t & 31;
  const int b = row >> 11;               // Q = 2048
  const float* ap = attnw + ((size_t)row * 8 + h) * 16;
  const float* lp = loc + ((size_t)row * 8 + h) * 32;
  const int col = h * 32 + d;
  const size_t vb = (size_t)b * LEN_IN_;
  const int starts[4] = {0, 10000, 12500, 13125};
  const int HWs[4]    = {100, 50, 25, 13};
  float acc = 0.f;
#pragma unroll
  for (int lv = 0; lv < 4; ++lv) {
    const int Wl = HWs[lv];
    const float Wf = (float)Wl;
    const size_t lvb = vb + starts[lv];
#pragma unroll
    for (int p = 0; p < 4; ++p) {
      const float lx = lp[(lv * 4 + p) * 2 + 0];
      const float ly = lp[(lv * 4 + p) * 2 + 1];
      const float aw = ap[lv * 4 + p];
      const float xx = lx * Wf - 0.5f, yy = ly * Wf - 0.5f;
      const float xf = floorf(xx), yf = floorf(yy);
      const float wx = xx - xf, wy = yy - yf;
      const int x0 = (int)xf, y0 = (int)yf, x1 = x0 + 1, y1 = y0 + 1;
      const int xc0 = min(max(x0, 0), Wl - 1), xc1 = min(max(x1, 0), Wl - 1);
      const int yc0 = min(max(y0, 0), Wl - 1), yc1 = min(max(y1, 0), Wl - 1);
      const float vx0 = (x0 >= 0 && x0 < Wl) ? 1.f : 0.f;
      const float vx1 = (x1 >= 0 && x1 < Wl) ? 1.f : 0.f;
      const float vy0 = (y0 >= 0 && y0 < Wl) ? 1.f : 0.f;
      const float vy1 = (y1 >= 0 && y1 < Wl) ? 1.f : 0.f;
      const float g00 = bf2f(value[(lvb + yc0 * Wl + xc0) * 256 + col]) * (vx0 * vy0);
      const float g01 = bf2f(value[(lvb + yc0 * Wl + xc1) * 256 + col]) * (vx1 * vy0);
      const float g10 = bf2f(value[(lvb + yc1 * Wl + xc0) * 256 + col]) * (vx0 * vy1);
      const float g11 = bf2f(value[(lvb + yc1 * Wl + xc1) * 256 + col]) * (vx1 * vy1);
      const float val = g00 * (1.f - wx) * (1.f - wy) + g01 * wx * (1.f - wy)
                      + g10 * (1.f - wx) * wy         + g11 * wx * wy;
      acc += aw * val;
    }
  }
  outp[(size_t)row * 256 + col] = f2bf(acc);
}

// ---------------- launch ----------------
extern "C" void kernel_launch(void* const* d_in, const int* in_sizes, int n_in,
                              void* d_out, int out_size, void* d_ws, size_t ws_size,
                              hipStream_t stream)
{
  (void)in_sizes; (void)n_in; (void)out_size; (void)ws_size;
  const float* input  = (const float*)d_in[0];
  const float* pos    = (const float*)d_in[1];
  const float* refpt  = (const float*)d_in[2];
  const float* source = (const float*)d_in[3];
  const float* ln1_g  = (const float*)d_in[7];
  const float* ln1_b  = (const float*)d_in[8];
  const float* ln2_g  = (const float*)d_in[9];
  const float* ln2_b  = (const float*)d_in[10];
  const float* Wv     = (const float*)d_in[11];
  const float* bv     = (const float*)d_in[12];
  const float* Woff   = (const float*)d_in[13];
  const float* boff   = (const float*)d_in[14];
  const float* Wattn  = (const float*)d_in[15];
  const float* battn  = (const float*)d_in[16];
  const float* Wout   = (const float*)d_in[17];
  const float* bout   = (const float*)d_in[18];
  const float* W1     = (const float*)d_in[19];
  const float* b1     = (const float*)d_in[20];
  const float* W2     = (const float*)d_in[21];
  const float* b2     = (const float*)d_in[22];

  char* ws = (char*)d_ws;
  u16*   WvT    = (u16*)  (ws + 0);           // 131072 B
  u16*   WoffT  = (u16*)  (ws + 131072);      // 131072 B
  u16*   WattnT = (u16*)  (ws + 262144);      // 65536 B
  u16*   WoutT  = (u16*)  (ws + 327680);      // 131072 B
  u16*   W1T    = (u16*)  (ws + 458752);      // 524288 B
  u16*   W2T    = (u16*)  (ws + 983040);      // 524288 B
  u16*   valueB = (u16*)  (ws + 1507328);     // 54,460,416 B (MVPAD x 256 bf16)
  u16*   qpB    = (u16*)  (ws + 55967744);    // 8,388,608 B
  float* attnw  = (float*)(ws + 64356352);    // 8,388,608 B (raw then softmax in-place)
  u16*   msout  = (u16*)  (ws + 72744960);    // 8,388,608 B
  float* xbuf   = (float*)(ws + 81133568);    // 16,777,216 B
  u16*   xnB    = (u16*)  (ws + 97910784);    // 8,388,608 B
  u16*   srcB   = (u16*)  (ws + 106299392);   // 54,460,416 B (reused below)
  float* offraw = (float*)(ws + 106299392);   // 16,777,216 B (after value GEMM)
  u16*   hB     = (u16*)  (ws + 123076608);   // 33,554,432 B

  float* out_x   = (float*)d_out;                 // 4,194,304 floats
  float* out_loc = (float*)d_out + (size_t)MQ * DIM_;

  // weights -> bf16 transposed [N][K]
  hipLaunchKernelGGL(transpose_w, dim3(256),  dim3(256), 0, stream, Wv,   WvT,    256, 256);
  hipLaunchKernelGGL(transpose_w, dim3(256),  dim3(256), 0, stream, Woff, WoffT,  256, 256);
  hipLaunchKernelGGL(transpose_w, dim3(128),  dim3(256), 0, stream, Wattn,WattnT, 256, 128);
  hipLaunchKernelGGL(transpose_w, dim3(256),  dim3(256), 0, stream, Wout, WoutT,  256, 256);
  hipLaunchKernelGGL(transpose_w, dim3(1024), dim3(256), 0, stream, W1,   W1T,    256, 1024);
  hipLaunchKernelGGL(transpose_w, dim3(1024), dim3(256), 0, stream, W2,   W2T,    1024, 256);

  // source -> bf16 (padded to MVPAD rows)
  hipLaunchKernelGGL(cvt_src, dim3((MVPAD * DIM_) / 1024), dim3(256), 0, stream, source, srcB);

  // qp = LN1(input)*g+b + pos   (bf16)
  hipLaunchKernelGGL((ln_k<true>), dim3(MQ / 4), dim3(256), 0, stream, input, pos, ln1_g, ln1_b, qpB);

  // value = source @ Wv + bv  (bf16 out)
  hipLaunchKernelGGL((gemm_k<1>), dim3(MVPAD / 128, 2), dim3(256), 0, stream,
                     srcB, WvT, bv, (const float*)nullptr, (void*)valueB, 256, 256, MV);

  // offsets raw = qp @ Woff + boff (f32)   [overwrites srcB region — safe, after value GEMM]
  hipLaunchKernelGGL((gemm_k<0>), dim3(MQ / 128, 2), dim3(256), 0, stream,
                     qpB, WoffT, boff, (const float*)nullptr, (void*)offraw, 256, 256, MQ);

  // attn raw = qp @ Wattn + battn (f32)
  hipLaunchKernelGGL((gemm_k<0>), dim3(MQ / 128, 1), dim3(256), 0, stream,
                     qpB, WattnT, battn, (const float*)nullptr, (void*)attnw, 128, 256, MQ);

  // softmax over 16 per (b,q,h), in place
  hipLaunchKernelGGL(softmax16, dim3(MQ * NH / 256), dim3(256), 0, stream, attnw);

  // loc (output 1)
  hipLaunchKernelGGL(loc_k, dim3(MQ * NH * 16 / 256), dim3(256), 0, stream, offraw, refpt, out_loc);

  // deformable sampling -> msout (bf16)
  hipLaunchKernelGGL(msdeform_k, dim3(MQ), dim3(256), 0, stream, valueB, attnw, out_loc, msout);

  // x = input + msout @ Wout + bout (f32)
  hipLaunchKernelGGL((gemm_k<2>), dim3(MQ / 128, 2), dim3(256), 0, stream,
                     msout, WoutT, bout, input, (void*)xbuf, 256, 256, MQ);

  // xn = LN2(x) (bf16)
  hipLaunchKernelGGL((ln_k<false>), dim3(MQ / 4), dim3(256), 0, stream, xbuf, (const float*)nullptr, ln2_g, ln2_b, xnB);

  // h = relu(xn @ W1 + b1) (bf16)
  hipLaunchKernelGGL((gemm_k<3>), dim3(MQ / 128, DFF / 128), dim3(256), 0, stream,
                     xnB, W1T, b1, (const float*)nullptr, (void*)hB, DFF, 256, MQ);

  // out_x = x + h @ W2 + b2 (f32)
  hipLaunchKernelGGL((gemm_k<2>), dim3(MQ / 128, 2), dim3(256), 0, stream,
                     hB, W2T, b2, xbuf, (void*)out_x, 256, 1024, MQ);
}

// Round 2
// 459.901 us; speedup vs baseline: 1.1415x; 1.1415x over previous
//
#include <hip/hip_runtime.h>
#include <hip/hip_bf16.h>
#include <cstdint>
#include <cstddef>

// ---------------- problem constants ----------------
#define B_    8
#define Q_    2048
#define DIM_  256
#define NH    8
#define HD    32
#define NL    4
#define NP    4
#define DFF   1024
#define LEN_IN_ 13294
#define MV    (B_*LEN_IN_)     // 106352
#define MVPAD 106368           // 831*128
#define MQ    (B_*Q_)          // 16384

typedef unsigned short u16;
typedef unsigned int   u32;
typedef __attribute__((ext_vector_type(8))) short short8;
typedef __attribute__((ext_vector_type(4))) float f32x4v;
typedef __attribute__((ext_vector_type(4))) unsigned short u16x4;

static __device__ __forceinline__ u16 f2bf(float f){
  union { float f; unsigned u; } x; x.f = f;
  unsigned r = x.u + 0x7fffu + ((x.u >> 16) & 1u);
  return (u16)(r >> 16);
}

// ---------------- generic bf16 MFMA GEMM ----------------
// C[M][N] = A[M][K] @ Bt[N][K]^T + bias ; A,Bt bf16 row-major; acc fp32.
// EPI: 0 = f32 store (+bias); 1 = bf16 store (+bias);
//      2 = f32 store (+bias + residual); 3 = bf16 store (+bias + relu)
template<int EPI>
__global__ __launch_bounds__(256)
void gemm_k(const u16* __restrict__ A, const u16* __restrict__ Bt,
            const float* __restrict__ bias, const float* __restrict__ res,
            void* __restrict__ outp, int N, int K, int Mstore)
{
  __shared__ u16 As[128*64];
  __shared__ u16 Bs[128*64];
  const int t = threadIdx.x;
  const int l = t & 63, wid = t >> 6;
  const int wm = wid >> 1, wn = wid & 1;
  const int m0 = blockIdx.x * 128, n0 = blockIdx.y * 128;

  f32x4v acc[4][4];
#pragma unroll
  for (int i = 0; i < 4; ++i)
#pragma unroll
    for (int j = 0; j < 4; ++j) acc[i][j] = 0.f;

  const int nkt = K >> 6;
  for (int kt = 0; kt < nkt; ++kt) {
#pragma unroll
    for (int i = 0; i < 4; ++i) {
      int chunk = i * 256 + t;          // 0..1023 16B-chunks
      int row   = chunk >> 3;           // 8 chunks per 64-col row
      int c16   = chunk & 7;
      int sc    = c16 ^ (row & 7);      // inverse swizzle on SOURCE, linear LDS dest
      const u16* ga = A  + (size_t)(m0 + row) * K + kt * 64 + sc * 8;
      __builtin_amdgcn_global_load_lds((const __attribute__((address_space(1))) void*)ga,
                                       (__attribute__((address_space(3))) void*)(As + chunk * 8), 16, 0, 0);
      const u16* gb = Bt + (size_t)(n0 + row) * K + kt * 64 + sc * 8;
      __builtin_amdgcn_global_load_lds((const __attribute__((address_space(1))) void*)gb,
                                       (__attribute__((address_space(3))) void*)(Bs + chunk * 8), 16, 0, 0);
    }
    __syncthreads();
#pragma unroll
    for (int kk = 0; kk < 2; ++kk) {
      short8 af[4], bfr[4];
      const int lr  = l & 15;
      const int c   = kk * 4 + (l >> 4);
      const int swz = c ^ (lr & 7);
#pragma unroll
      for (int mi = 0; mi < 4; ++mi) {
        int r = wm * 64 + mi * 16 + lr;
        af[mi] = *reinterpret_cast<const short8*>(As + (r * 8 + swz) * 8);
      }
#pragma unroll
      for (int ni = 0; ni < 4; ++ni) {
        int r = wn * 64 + ni * 16 + lr;
        bfr[ni] = *reinterpret_cast<const short8*>(Bs + (r * 8 + swz) * 8);
      }
#pragma unroll
      for (int mi = 0; mi < 4; ++mi)
#pragma unroll
        for (int ni = 0; ni < 4; ++ni)
          acc[mi][ni] = __builtin_amdgcn_mfma_f32_16x16x32_bf16(af[mi], bfr[ni], acc[mi][ni], 0, 0, 0);
    }
    __syncthreads();
  }

  const int lr4 = l >> 4;
#pragma unroll
  for (int mi = 0; mi < 4; ++mi) {
    int rowb = m0 + wm * 64 + mi * 16 + lr4 * 4;
#pragma unroll
    for (int ni = 0; ni < 4; ++ni) {
      int col = n0 + wn * 64 + ni * 16 + (l & 15);
      float bb = bias[col];
#pragma unroll
      for (int v = 0; v < 4; ++v) {
        int r = rowb + v;
        if (r < Mstore) {
          float cv = acc[mi][ni][v] + bb;
          if (EPI == 2) cv += res[(size_t)r * N + col];
          if (EPI == 3) cv = fmaxf(cv, 0.f);
          if (EPI == 0 || EPI == 2) ((float*)outp)[(size_t)r * N + col] = cv;
          else                      ((u16*)outp)[(size_t)r * N + col] = f2bf(cv);
        }
      }
    }
  }
}

// ---------------- fused weight prep: all transposes + combined bias ----------------
// WvT[256][256], WcombT[384][256] (rows 0-255 Woff cols, 256-383 Wattn cols),
// WoutT[256][256], W1T[1024][256], W2T[256][1024], bcomb[384]
__global__ void prep_weights(const float* __restrict__ Wv,   const float* __restrict__ Woff,
                             const float* __restrict__ Wattn,const float* __restrict__ Wout,
                             const float* __restrict__ W1,   const float* __restrict__ W2,
                             const float* __restrict__ boff, const float* __restrict__ battn,
                             u16* __restrict__ WvT, u16* __restrict__ WcombT,
                             u16* __restrict__ WoutT, u16* __restrict__ W1T,
                             u16* __restrict__ W2T, float* __restrict__ bcomb)
{
  const int gid = blockIdx.x * 256 + threadIdx.x;
  const int R0 = 65536, R1 = R0 + 98304, R2 = R1 + 65536, R3 = R2 + 262144,
            R4 = R3 + 262144, R5 = R4 + 384;
  if (gid < R0) {
    int n = gid >> 8, k = gid & 255;
    WvT[gid] = f2bf(Wv[(size_t)k * 256 + n]);
  } else if (gid < R1) {
    int lo = gid - R0, n = lo >> 8, k = lo & 255;
    float s = (n < 256) ? Woff[(size_t)k * 256 + n] : Wattn[(size_t)k * 128 + (n - 256)];
    WcombT[lo] = f2bf(s);
  } else if (gid < R2) {
    int lo = gid - R1, n = lo >> 8, k = lo & 255;
    WoutT[lo] = f2bf(Wout[(size_t)k * 256 + n]);
  } else if (gid < R3) {
    int lo = gid - R2, n = lo >> 8, k = lo & 255;
    W1T[lo] = f2bf(W1[(size_t)k * 1024 + n]);
  } else if (gid < R4) {
    int lo = gid - R3, n = lo >> 10, k = lo & 1023;
    W2T[lo] = f2bf(W2[(size_t)k * 256 + n]);
  } else if (gid < R5) {
    int lo = gid - R4;
    bcomb[lo] = (lo < 256) ? boff[lo] : battn[lo - 256];
  }
}

// ---------------- source fp32 -> bf16 (+ zero pad rows) ----------------
__global__ void cvt_src(const float* __restrict__ src, u16* __restrict__ dst)
{
  size_t gid = (size_t)blockIdx.x * 256 + threadIdx.x;   // per float4 group
  size_t base = gid * 4;
  const size_t nsrc = (size_t)MV * DIM_;
  u16x4 o;
  if (base < nsrc) {
    const float4 v = reinterpret_cast<const float4*>(src)[gid];
    o.x = f2bf(v.x); o.y = f2bf(v.y); o.z = f2bf(v.z); o.w = f2bf(v.w);
  } else {
    o.x = 0; o.y = 0; o.z = 0; o.w = 0;
  }
  *reinterpret_cast<u16x4*>(dst + base) = o;
}

// ---------------- LayerNorm (warp per 256-float row) -> bf16 out ----------------
template<bool ADDPOS>
__global__ __launch_bounds__(256)
void ln_k(const float* __restrict__ x, const float* __restrict__ pos,
          const float* __restrict__ g, const float* __restrict__ b, u16* __restrict__ out)
{
  const int warp = threadIdx.x >> 6, l = threadIdx.x & 63;
  const int row = blockIdx.x * 4 + warp;
  const float4 xv = reinterpret_cast<const float4*>(x + (size_t)row * 256)[l];
  float s = xv.x + xv.y + xv.z + xv.w;
#pragma unroll
  for (int o = 32; o; o >>= 1) s += __shfl_xor(s, o);
  const float mean = s * (1.f / 256.f);
  const float d0 = xv.x - mean, d1 = xv.y - mean, d2 = xv.z - mean, d3 = xv.w - mean;
  float vs = d0 * d0 + d1 * d1 + d2 * d2 + d3 * d3;
#pragma unroll
  for (int o = 32; o; o >>= 1) vs += __shfl_xor(vs, o);
  const float rs = rsqrtf(vs * (1.f / 256.f) + 1e-5f);
  const float4 gv = reinterpret_cast<const float4*>(g)[l];
  const float4 bv = reinterpret_cast<const float4*>(b)[l];
  float o0 = d0 * rs * gv.x + bv.x;
  float o1 = d1 * rs * gv.y + bv.y;
  float o2 = d2 * rs * gv.z + bv.z;
  float o3 = d3 * rs * gv.w + bv.w;
  if (ADDPOS) {
    const float4 pv = reinterpret_cast<const float4*>(pos + (size_t)row * 256)[l];
    o0 += pv.x; o1 += pv.y; o2 += pv.z; o3 += pv.w;
  }
  u16x4 ov; ov.x = f2bf(o0); ov.y = f2bf(o1); ov.z = f2bf(o2); ov.w = f2bf(o3);
  reinterpret_cast<u16x4*>(out + (size_t)row * 256)[l] = ov;
}

// ---------------- fused softmax(attn) + loc  (one thread per (row,h)) ----------------
// oa[row][384]: cols 0-255 offsets raw (h*32 + lv*8 + pt*2 + xy), 256-383 attn raw.
__global__ __launch_bounds__(256)
void locsoft(const float* __restrict__ oa, const float* __restrict__ refpt,
             float* __restrict__ attnw, float* __restrict__ locout)
{
  const int gh = blockIdx.x * 256 + threadIdx.x;   // row*8 + h
  const int row = gh >> 3, h = gh & 7;
  const float* orow = oa + (size_t)row * 384;
  // softmax over 16
  float v[16];
#pragma unroll
  for (int i = 0; i < 16; ++i) v[i] = orow[256 + h * 16 + i];
  float m = v[0];
#pragma unroll
  for (int i = 1; i < 16; ++i) m = fmaxf(m, v[i]);
  float s = 0.f;
#pragma unroll
  for (int i = 0; i < 16; ++i) { v[i] = __expf(v[i] - m); s += v[i]; }
  const float inv = 1.f / s;
  float* ap = attnw + (size_t)gh * 16;
#pragma unroll
  for (int i = 0; i < 16; ++i) ap[i] = v[i] * inv;
  // loc
  float* lp = locout + (size_t)gh * 32;
#pragma unroll
  for (int i = 0; i < 16; ++i) {
    const int lv = i >> 2;
    const float rn = (lv == 0) ? (1.f / 100.f) : (lv == 1) ? (1.f / 50.f)
                   : (lv == 2) ? (1.f / 25.f) : (1.f / 13.f);
    const float ox = orow[h * 32 + i * 2 + 0];
    const float oy = orow[h * 32 + i * 2 + 1];
    const float rx = refpt[(size_t)row * 8 + lv * 2 + 0];
    const float ry = refpt[(size_t)row * 8 + lv * 2 + 1];
    lp[i * 2 + 0] = rx + ox * rn;
    lp[i * 2 + 1] = ry + oy * rn;
  }
}

// ---------------- multiscale deformable sampling (v2) ----------------
// Block = 256 threads = 2 rows x 8 heads x 16 lanes. Each lane owns 2 dims
// (one u32 load per corner) AND computes one point's params; params are
// broadcast across the 16-lane group via __shfl(.,q,16).
__global__ __launch_bounds__(256)
void msdeform_k(const u16* __restrict__ value, const float* __restrict__ attnw,
                const float* __restrict__ loc, u16* __restrict__ outp)
{
  const int t = threadIdx.x;
  const int rloc = t >> 7;              // row within block
  const int rem = t & 127;
  const int h = rem >> 4, p = rem & 15; // p = lane-in-group = point idx = dim-pair idx
  const int row = blockIdx.x * 2 + rloc;
  const int b = row >> 11;              // Q=2048
  const int lv = p >> 2;

  // ---- this lane's point params
  const float2 lxy = *reinterpret_cast<const float2*>(loc + (((size_t)row * 8 + h) * 16 + p) * 2);
  const float aw = attnw[((size_t)row * 8 + h) * 16 + p];
  const int Wl = (lv == 0) ? 100 : (lv == 1) ? 50 : (lv == 2) ? 25 : 13;
  const int st = (lv == 0) ? 0 : (lv == 1) ? 10000 : (lv == 2) ? 12500 : 13125;
  const float Wf = (float)Wl;
  const float xx = lxy.x * Wf - 0.5f, yy = lxy.y * Wf - 0.5f;
  const float xf = floorf(xx), yf = floorf(yy);
  const float wx = xx - xf, wy = yy - yf;
  const int x0 = (int)xf, y0 = (int)yf;
  const int xc0 = min(max(x0, 0), Wl - 1), xc1 = min(max(x0 + 1, 0), Wl - 1);
  const int yc0 = min(max(y0, 0), Wl - 1), yc1 = min(max(y0 + 1, 0), Wl - 1);
  const float vx0 = (x0 >= 0 && x0 < Wl) ? 1.f : 0.f;
  const float vx1 = (x0 + 1 >= 0 && x0 + 1 < Wl) ? 1.f : 0.f;
  const float vy0 = (y0 >= 0 && y0 < Wl) ? 1.f : 0.f;
  const float vy1 = (y0 + 1 >= 0 && y0 + 1 < Wl) ? 1.f : 0.f;
  const int o00 = st + yc0 * Wl + xc0, o01 = st + yc0 * Wl + xc1;
  const int o10 = st + yc1 * Wl + xc0, o11 = st + yc1 * Wl + xc1;
  const float w00 = aw * (1.f - wx) * (1.f - wy) * vx0 * vy0;
  const float w01 = aw * wx * (1.f - wy) * vx1 * vy0;
  const float w10 = aw * (1.f - wx) * wy * vx0 * vy1;
  const float w11 = aw * wx * wy * vx1 * vy1;

  const char* vbase = (const char*)value + (size_t)b * LEN_IN_ * 512 + (size_t)(h * 32 + p * 2) * 2;
  float a0 = 0.f, a1 = 0.f;
#pragma unroll
  for (int q = 0; q < 16; ++q) {
    const int   c00 = __shfl(o00, q, 16), c01 = __shfl(o01, q, 16);
    const int   c10 = __shfl(o10, q, 16), c11 = __shfl(o11, q, 16);
    const float u00 = __shfl(w00, q, 16), u01 = __shfl(w01, q, 16);
    const float u10 = __shfl(w10, q, 16), u11 = __shfl(w11, q, 16);
    const u32 g00 = *reinterpret_cast<const u32*>(vbase + (size_t)c00 * 512);
    const u32 g01 = *reinterpret_cast<const u32*>(vbase + (size_t)c01 * 512);
    const u32 g10 = *reinterpret_cast<const u32*>(vbase + (size_t)c10 * 512);
    const u32 g11 = *reinterpret_cast<const u32*>(vbase + (size_t)c11 * 512);
    union { u32 u; float f; } lo, hi;
    lo.u = g00 << 16; hi.u = g00 & 0xffff0000u; a0 += u00 * lo.f; a1 += u00 * hi.f;
    lo.u = g01 << 16; hi.u = g01 & 0xffff0000u; a0 += u01 * lo.f; a1 += u01 * hi.f;
    lo.u = g10 << 16; hi.u = g10 & 0xffff0000u; a0 += u10 * lo.f; a1 += u10 * hi.f;
    lo.u = g11 << 16; hi.u = g11 & 0xffff0000u; a0 += u11 * lo.f; a1 += u11 * hi.f;
  }
  const u32 res = ((u32)f2bf(a1) << 16) | (u32)f2bf(a0);
  reinterpret_cast<u32*>(outp)[(size_t)row * 128 + h * 16 + p] = res;
}

// ---------------- launch ----------------
extern "C" void kernel_launch(void* const* d_in, const int* in_sizes, int n_in,
                              void* d_out, int out_size, void* d_ws, size_t ws_size,
                              hipStream_t stream)
{
  (void)in_sizes; (void)n_in; (void)out_size; (void)ws_size;
  const float* input  = (const float*)d_in[0];
  const float* pos    = (const float*)d_in[1];
  const float* refpt  = (const float*)d_in[2];
  const float* source = (const float*)d_in[3];
  const float* ln1_g  = (const float*)d_in[7];
  const float* ln1_b  = (const float*)d_in[8];
  const float* ln2_g  = (const float*)d_in[9];
  const float* ln2_b  = (const float*)d_in[10];
  const float* Wv     = (const float*)d_in[11];
  const float* bv     = (const float*)d_in[12];
  const float* Woff   = (const float*)d_in[13];
  const float* boff   = (const float*)d_in[14];
  const float* Wattn  = (const float*)d_in[15];
  const float* battn  = (const float*)d_in[16];
  const float* Wout   = (const float*)d_in[17];
  const float* bout   = (const float*)d_in[18];
  const float* W1     = (const float*)d_in[19];
  const float* b1     = (const float*)d_in[20];
  const float* W2     = (const float*)d_in[21];
  const float* b2     = (const float*)d_in[22];

  char* ws = (char*)d_ws;
  u16*   WvT    = (u16*)  (ws + 0);           // 131072
  u16*   WcombT = (u16*)  (ws + 131072);      // 196608 ([384][256])
  u16*   WoutT  = (u16*)  (ws + 327680);      // 131072
  u16*   W1T    = (u16*)  (ws + 458752);      // 524288
  u16*   W2T    = (u16*)  (ws + 983040);      // 524288
  float* bcomb  = (float*)(ws + 1507328);     // 1536
  u16*   valueB = (u16*)  (ws + 1508864);     // 54,460,416 (MVPAD x 256 bf16)
  u16*   hB     = (u16*)  (ws + 1508864);     // 33,554,432 — reuses valueB (dead after msdeform)
  u16*   qpB    = (u16*)  (ws + 55969280);    // 8,388,608
  u16*   msout  = (u16*)  (ws + 55969280);    // 8,388,608 — reuses qpB (dead after comb GEMM)
  float* attnw  = (float*)(ws + 64357888);    // 8,388,608
  float* xbuf   = (float*)(ws + 72746496);    // 16,777,216
  u16*   xnB    = (u16*)  (ws + 89523712);    // 8,388,608
  u16*   srcB   = (u16*)  (ws + 97912320);    // 54,460,416
  float* oa     = (float*)(ws + 97912320);    // 25,165,824 — reuses srcB (dead after value GEMM)
  // total: 152,372,736 B

  float* out_x   = (float*)d_out;
  float* out_loc = (float*)d_out + (size_t)MQ * DIM_;

  // all weight transposes + combined bias, one kernel
  hipLaunchKernelGGL(prep_weights, dim3(2946), dim3(256), 0, stream,
                     Wv, Woff, Wattn, Wout, W1, W2, boff, battn,
                     WvT, WcombT, WoutT, W1T, W2T, bcomb);

  // source -> bf16 (padded to MVPAD rows)
  hipLaunchKernelGGL(cvt_src, dim3((MVPAD * DIM_) / 1024), dim3(256), 0, stream, source, srcB);

  // qp = LN1(input)*g+b + pos   (bf16)
  hipLaunchKernelGGL((ln_k<true>), dim3(MQ / 4), dim3(256), 0, stream, input, pos, ln1_g, ln1_b, qpB);

  // value = source @ Wv + bv  (bf16 out)
  hipLaunchKernelGGL((gemm_k<1>), dim3(MVPAD / 128, 2), dim3(256), 0, stream,
                     srcB, WvT, bv, (const float*)nullptr, (void*)valueB, 256, 256, MV);

  // [offsets|attn] raw = qp @ Wcomb + bcomb (f32, N=384)
  hipLaunchKernelGGL((gemm_k<0>), dim3(MQ / 128, 3), dim3(256), 0, stream,
                     qpB, WcombT, bcomb, (const float*)nullptr, (void*)oa, 384, 256, MQ);

  // softmax + loc (writes output 1)
  hipLaunchKernelGGL(locsoft, dim3(MQ * NH / 256), dim3(256), 0, stream, oa, refpt, attnw, out_loc);

  // deformable sampling -> msout (bf16)
  hipLaunchKernelGGL(msdeform_k, dim3(MQ / 2), dim3(256), 0, stream, valueB, attnw, out_loc, msout);

  // x = input + msout @ Wout + bout (f32)
  hipLaunchKernelGGL((gemm_k<2>), dim3(MQ / 128, 2), dim3(256), 0, stream,
                     msout, WoutT, bout, input, (void*)xbuf, 256, 256, MQ);

  // xn = LN2(x) (bf16)
  hipLaunchKernelGGL((ln_k<false>), dim3(MQ / 4), dim3(256), 0, stream, xbuf, (const float*)nullptr, ln2_g, ln2_b, xnB);

  // h = relu(xn @ W1 + b1) (bf16)
  hipLaunchKernelGGL((gemm_k<3>), dim3(MQ / 128, DFF / 128), dim3(256), 0, stream,
                     xnB, W1T, b1, (const float*)nullptr, (void*)hB, DFF, 256, MQ);

  // out_x = x + h @ W2 + b2 (f32)
  hipLaunchKernelGGL((gemm_k<2>), dim3(MQ / 128, 2), dim3(256), 0, stream,
                     hB, W2T, b2, xbuf, (void*)out_x, 256, 1024, MQ);
}

// Round 3
// 430.558 us; speedup vs baseline: 1.2193x; 1.0682x over previous
//
#include <hip/hip_runtime.h>
#include <hip/hip_bf16.h>
#include <cstdint>
#include <cstddef>

// ---------------- problem constants ----------------
#define B_    8
#define Q_    2048
#define DIM_  256
#define NH    8
#define HD    32
#define NL    4
#define NP    4
#define DFF   1024
#define LEN_IN_ 13294
#define MV    (B_*LEN_IN_)     // 106352
#define MVPAD 106368           // 831*128
#define MQ    (B_*Q_)          // 16384

typedef unsigned short u16;
typedef unsigned int   u32;
typedef __attribute__((ext_vector_type(8))) short short8;
typedef __attribute__((ext_vector_type(4))) float f32x4v;
typedef __attribute__((ext_vector_type(4))) unsigned short u16x4;

static __device__ __forceinline__ u16 f2bf(float f){
  union { float f; unsigned u; } x; x.f = f;
  unsigned r = x.u + 0x7fffu + ((x.u >> 16) & 1u);
  return (u16)(r >> 16);
}

// ---------------- generic bf16 MFMA GEMM ----------------
// C[M][N] = A[M][K] @ Bt[N][K]^T + bias ; Bt bf16 row-major [N][K]; acc fp32.
// AF32: A is fp32 (converted to bf16 during reg-staged LDS write, rows >= Mstore read as 0)
// EPI: 0 = f32 store (+bias); 1 = bf16 store (+bias);
//      2 = f32 store (+bias + residual); 3 = bf16 store (+bias + relu)
template<int EPI, bool AF32>
__global__ __launch_bounds__(256)
void gemm_k(const void* __restrict__ Ap, const u16* __restrict__ Bt,
            const float* __restrict__ bias, const float* __restrict__ res,
            void* __restrict__ outp, int N, int K, int Mstore)
{
  __shared__ u16 As[128*64];
  __shared__ u16 Bs[128*64];
  const int t = threadIdx.x;
  const int l = t & 63, wid = t >> 6;
  const int wm = wid >> 1, wn = wid & 1;
  const int m0 = blockIdx.x * 128, n0 = blockIdx.y * 128;

  f32x4v acc[4][4];
#pragma unroll
  for (int i = 0; i < 4; ++i)
#pragma unroll
    for (int j = 0; j < 4; ++j) acc[i][j] = 0.f;

  const int nkt = K >> 6;
  for (int kt = 0; kt < nkt; ++kt) {
#pragma unroll
    for (int i = 0; i < 4; ++i) {
      int chunk = i * 256 + t;          // 0..1023 16B-chunks
      int row   = chunk >> 3;           // 8 chunks per 64-col row
      int c16   = chunk & 7;
      int sc    = c16 ^ (row & 7);      // inverse swizzle on SOURCE, linear LDS dest
      if (AF32) {
        const int gr = m0 + row;
        float4 f0 = {0.f,0.f,0.f,0.f}, f1 = {0.f,0.f,0.f,0.f};
        if (gr < Mstore) {
          const float* ga = (const float*)Ap + (size_t)gr * K + kt * 64 + sc * 8;
          f0 = *reinterpret_cast<const float4*>(ga);
          f1 = *reinterpret_cast<const float4*>(ga + 4);
        }
        short8 pk;
        pk[0]=(short)f2bf(f0.x); pk[1]=(short)f2bf(f0.y); pk[2]=(short)f2bf(f0.z); pk[3]=(short)f2bf(f0.w);
        pk[4]=(short)f2bf(f1.x); pk[5]=(short)f2bf(f1.y); pk[6]=(short)f2bf(f1.z); pk[7]=(short)f2bf(f1.w);
        *reinterpret_cast<short8*>(As + chunk * 8) = pk;
      } else {
        const u16* ga = (const u16*)Ap + (size_t)(m0 + row) * K + kt * 64 + sc * 8;
        __builtin_amdgcn_global_load_lds((const __attribute__((address_space(1))) void*)ga,
                                         (__attribute__((address_space(3))) void*)(As + chunk * 8), 16, 0, 0);
      }
      const u16* gb = Bt + (size_t)(n0 + row) * K + kt * 64 + sc * 8;
      __builtin_amdgcn_global_load_lds((const __attribute__((address_space(1))) void*)gb,
                                       (__attribute__((address_space(3))) void*)(Bs + chunk * 8), 16, 0, 0);
    }
    __syncthreads();
#pragma unroll
    for (int kk = 0; kk < 2; ++kk) {
      short8 af[4], bfr[4];
      const int lr  = l & 15;
      const int c   = kk * 4 + (l >> 4);
      const int swz = c ^ (lr & 7);
#pragma unroll
      for (int mi = 0; mi < 4; ++mi) {
        int r = wm * 64 + mi * 16 + lr;
        af[mi] = *reinterpret_cast<const short8*>(As + (r * 8 + swz) * 8);
      }
#pragma unroll
      for (int ni = 0; ni < 4; ++ni) {
        int r = wn * 64 + ni * 16 + lr;
        bfr[ni] = *reinterpret_cast<const short8*>(Bs + (r * 8 + swz) * 8);
      }
#pragma unroll
      for (int mi = 0; mi < 4; ++mi)
#pragma unroll
        for (int ni = 0; ni < 4; ++ni)
          acc[mi][ni] = __builtin_amdgcn_mfma_f32_16x16x32_bf16(af[mi], bfr[ni], acc[mi][ni], 0, 0, 0);
    }
    __syncthreads();
  }

  const int lr4 = l >> 4;
#pragma unroll
  for (int mi = 0; mi < 4; ++mi) {
    int rowb = m0 + wm * 64 + mi * 16 + lr4 * 4;
#pragma unroll
    for (int ni = 0; ni < 4; ++ni) {
      int col = n0 + wn * 64 + ni * 16 + (l & 15);
      float bb = bias[col];
#pragma unroll
      for (int v = 0; v < 4; ++v) {
        int r = rowb + v;
        if (r < Mstore) {
          float cv = acc[mi][ni][v] + bb;
          if (EPI == 2) cv += res[(size_t)r * N + col];
          if (EPI == 3) cv = fmaxf(cv, 0.f);
          if (EPI == 0 || EPI == 2) ((float*)outp)[(size_t)r * N + col] = cv;
          else                      ((u16*)outp)[(size_t)r * N + col] = f2bf(cv);
        }
      }
    }
  }
}

// ---------------- fused weight prep: all transposes + combined bias ----------------
__global__ void prep_weights(const float* __restrict__ Wv,   const float* __restrict__ Woff,
                             const float* __restrict__ Wattn,const float* __restrict__ Wout,
                             const float* __restrict__ W1,   const float* __restrict__ W2,
                             const float* __restrict__ boff, const float* __restrict__ battn,
                             u16* __restrict__ WvT, u16* __restrict__ WcombT,
                             u16* __restrict__ WoutT, u16* __restrict__ W1T,
                             u16* __restrict__ W2T, float* __restrict__ bcomb)
{
  const int gid = blockIdx.x * 256 + threadIdx.x;
  const int R0 = 65536, R1 = R0 + 98304, R2 = R1 + 65536, R3 = R2 + 262144,
            R4 = R3 + 262144, R5 = R4 + 384;
  if (gid < R0) {
    int n = gid >> 8, k = gid & 255;
    WvT[gid] = f2bf(Wv[(size_t)k * 256 + n]);
  } else if (gid < R1) {
    int lo = gid - R0, n = lo >> 8, k = lo & 255;
    float s = (n < 256) ? Woff[(size_t)k * 256 + n] : Wattn[(size_t)k * 128 + (n - 256)];
    WcombT[lo] = f2bf(s);
  } else if (gid < R2) {
    int lo = gid - R1, n = lo >> 8, k = lo & 255;
    WoutT[lo] = f2bf(Wout[(size_t)k * 256 + n]);
  } else if (gid < R3) {
    int lo = gid - R2, n = lo >> 8, k = lo & 255;
    W1T[lo] = f2bf(W1[(size_t)k * 1024 + n]);
  } else if (gid < R4) {
    int lo = gid - R3, n = lo >> 10, k = lo & 1023;
    W2T[lo] = f2bf(W2[(size_t)k * 256 + n]);
  } else if (gid < R5) {
    int lo = gid - R4;
    bcomb[lo] = (lo < 256) ? boff[lo] : battn[lo - 256];
  }
}

// ---------------- LayerNorm (warp per 256-float row) -> bf16 out ----------------
template<bool ADDPOS>
__global__ __launch_bounds__(256)
void ln_k(const float* __restrict__ x, const float* __restrict__ pos,
          const float* __restrict__ g, const float* __restrict__ b, u16* __restrict__ out)
{
  const int warp = threadIdx.x >> 6, l = threadIdx.x & 63;
  const int row = blockIdx.x * 4 + warp;
  const float4 xv = reinterpret_cast<const float4*>(x + (size_t)row * 256)[l];
  float s = xv.x + xv.y + xv.z + xv.w;
#pragma unroll
  for (int o = 32; o; o >>= 1) s += __shfl_xor(s, o);
  const float mean = s * (1.f / 256.f);
  const float d0 = xv.x - mean, d1 = xv.y - mean, d2 = xv.z - mean, d3 = xv.w - mean;
  float vs = d0 * d0 + d1 * d1 + d2 * d2 + d3 * d3;
#pragma unroll
  for (int o = 32; o; o >>= 1) vs += __shfl_xor(vs, o);
  const float rs = rsqrtf(vs * (1.f / 256.f) + 1e-5f);
  const float4 gv = reinterpret_cast<const float4*>(g)[l];
  const float4 bv = reinterpret_cast<const float4*>(b)[l];
  float o0 = d0 * rs * gv.x + bv.x;
  float o1 = d1 * rs * gv.y + bv.y;
  float o2 = d2 * rs * gv.z + bv.z;
  float o3 = d3 * rs * gv.w + bv.w;
  if (ADDPOS) {
    const float4 pv = reinterpret_cast<const float4*>(pos + (size_t)row * 256)[l];
    o0 += pv.x; o1 += pv.y; o2 += pv.z; o3 += pv.w;
  }
  u16x4 ov; ov.x = f2bf(o0); ov.y = f2bf(o1); ov.z = f2bf(o2); ov.w = f2bf(o3);
  reinterpret_cast<u16x4*>(out + (size_t)row * 256)[l] = ov;
}

// ---------------- fused softmax + loc + multiscale deformable sampling ----------------
// Block = 256 threads = 2 rows x 8 heads x 16 lanes. Lane p owns point p:
// computes its softmax weight (shfl_xor reduce over the 16-lane group), its loc
// (written to output 1), then the group samples; each lane accumulates 2 dims.
__global__ __launch_bounds__(256)
void msdeform_k(const u16* __restrict__ value, const float* __restrict__ oa,
                const float* __restrict__ refpt, float* __restrict__ locout,
                u16* __restrict__ outp)
{
  const int t = threadIdx.x;
  const int rloc = t >> 7;              // row within block
  const int rem = t & 127;
  const int h = rem >> 4, p = rem & 15; // p = lane-in-group = point idx = dim-pair idx
  const int row = blockIdx.x * 2 + rloc;
  const int b = row >> 11;              // Q=2048
  const int lv = p >> 2;
  const float* orow = oa + (size_t)row * 384;

  // ---- softmax over the 16 points of (row,h)
  const float araw = orow[256 + h * 16 + p];
  float mx = araw;
#pragma unroll
  for (int o = 1; o < 16; o <<= 1) mx = fmaxf(mx, __shfl_xor(mx, o, 16));
  const float e = __expf(araw - mx);
  float se = e;
#pragma unroll
  for (int o = 1; o < 16; o <<= 1) se += __shfl_xor(se, o, 16);
  const float aw = e / se;

  // ---- loc = ref + off/normalizer  (write output 1)
  const float2 off = *reinterpret_cast<const float2*>(orow + h * 32 + p * 2);
  const float rn = (lv == 0) ? (1.f / 100.f) : (lv == 1) ? (1.f / 50.f)
                 : (lv == 2) ? (1.f / 25.f) : (1.f / 13.f);
  const float rx = refpt[(size_t)row * 8 + lv * 2 + 0];
  const float ry = refpt[(size_t)row * 8 + lv * 2 + 1];
  const float lx = rx + off.x * rn;
  const float ly = ry + off.y * rn;
  float2 lw; lw.x = lx; lw.y = ly;
  *reinterpret_cast<float2*>(locout + (((size_t)row * 8 + h) * 16 + p) * 2) = lw;

  // ---- this lane's point params
  const int Wl = (lv == 0) ? 100 : (lv == 1) ? 50 : (lv == 2) ? 25 : 13;
  const int st = (lv == 0) ? 0 : (lv == 1) ? 10000 : (lv == 2) ? 12500 : 13125;
  const float Wf = (float)Wl;
  const float xx = lx * Wf - 0.5f, yy = ly * Wf - 0.5f;
  const float xf = floorf(xx), yf = floorf(yy);
  const float wx = xx - xf, wy = yy - yf;
  const int x0 = (int)xf, y0 = (int)yf;
  const int xc0 = min(max(x0, 0), Wl - 1), xc1 = min(max(x0 + 1, 0), Wl - 1);
  const int yc0 = min(max(y0, 0), Wl - 1), yc1 = min(max(y0 + 1, 0), Wl - 1);
  const float vx0 = (x0 >= 0 && x0 < Wl) ? 1.f : 0.f;
  const float vx1 = (x0 + 1 >= 0 && x0 + 1 < Wl) ? 1.f : 0.f;
  const float vy0 = (y0 >= 0 && y0 < Wl) ? 1.f : 0.f;
  const float vy1 = (y0 + 1 >= 0 && y0 + 1 < Wl) ? 1.f : 0.f;
  const int o00 = st + yc0 * Wl + xc0, o01 = st + yc0 * Wl + xc1;
  const int o10 = st + yc1 * Wl + xc0, o11 = st + yc1 * Wl + xc1;
  const float w00 = aw * (1.f - wx) * (1.f - wy) * vx0 * vy0;
  const float w01 = aw * wx * (1.f - wy) * vx1 * vy0;
  const float w10 = aw * (1.f - wx) * wy * vx0 * vy1;
  const float w11 = aw * wx * wy * vx1 * vy1;

  const char* vbase = (const char*)value + (size_t)b * LEN_IN_ * 512 + (size_t)(h * 32 + p * 2) * 2;
  float a0 = 0.f, a1 = 0.f;
#pragma unroll
  for (int q = 0; q < 16; ++q) {
    const int   c00 = __shfl(o00, q, 16), c01 = __shfl(o01, q, 16);
    const int   c10 = __shfl(o10, q, 16), c11 = __shfl(o11, q, 16);
    const float u00 = __shfl(w00, q, 16), u01 = __shfl(w01, q, 16);
    const float u10 = __shfl(w10, q, 16), u11 = __shfl(w11, q, 16);
    const u32 g00 = *reinterpret_cast<const u32*>(vbase + (size_t)c00 * 512);
    const u32 g01 = *reinterpret_cast<const u32*>(vbase + (size_t)c01 * 512);
    const u32 g10 = *reinterpret_cast<const u32*>(vbase + (size_t)c10 * 512);
    const u32 g11 = *reinterpret_cast<const u32*>(vbase + (size_t)c11 * 512);
    union { u32 u; float f; } lo, hi;
    lo.u = g00 << 16; hi.u = g00 & 0xffff0000u; a0 += u00 * lo.f; a1 += u00 * hi.f;
    lo.u = g01 << 16; hi.u = g01 & 0xffff0000u; a0 += u01 * lo.f; a1 += u01 * hi.f;
    lo.u = g10 << 16; hi.u = g10 & 0xffff0000u; a0 += u10 * lo.f; a1 += u10 * hi.f;
    lo.u = g11 << 16; hi.u = g11 & 0xffff0000u; a0 += u11 * lo.f; a1 += u11 * hi.f;
  }
  const u32 res = ((u32)f2bf(a1) << 16) | (u32)f2bf(a0);
  reinterpret_cast<u32*>(outp)[(size_t)row * 128 + h * 16 + p] = res;
}

// ---------------- launch ----------------
extern "C" void kernel_launch(void* const* d_in, const int* in_sizes, int n_in,
                              void* d_out, int out_size, void* d_ws, size_t ws_size,
                              hipStream_t stream)
{
  (void)in_sizes; (void)n_in; (void)out_size; (void)ws_size;
  const float* input  = (const float*)d_in[0];
  const float* pos    = (const float*)d_in[1];
  const float* refpt  = (const float*)d_in[2];
  const float* source = (const float*)d_in[3];
  const float* ln1_g  = (const float*)d_in[7];
  const float* ln1_b  = (const float*)d_in[8];
  const float* ln2_g  = (const float*)d_in[9];
  const float* ln2_b  = (const float*)d_in[10];
  const float* Wv     = (const float*)d_in[11];
  const float* bv     = (const float*)d_in[12];
  const float* Woff   = (const float*)d_in[13];
  const float* boff   = (const float*)d_in[14];
  const float* Wattn  = (const float*)d_in[15];
  const float* battn  = (const float*)d_in[16];
  const float* Wout   = (const float*)d_in[17];
  const float* bout   = (const float*)d_in[18];
  const float* W1     = (const float*)d_in[19];
  const float* b1     = (const float*)d_in[20];
  const float* W2     = (const float*)d_in[21];
  const float* b2     = (const float*)d_in[22];

  char* ws = (char*)d_ws;
  u16*   WvT    = (u16*)  (ws + 0);           // 131072
  u16*   WcombT = (u16*)  (ws + 131072);      // 196608 ([384][256])
  u16*   WoutT  = (u16*)  (ws + 327680);      // 131072
  u16*   W1T    = (u16*)  (ws + 458752);      // 524288
  u16*   W2T    = (u16*)  (ws + 983040);      // 524288
  float* bcomb  = (float*)(ws + 1507328);     // 1536
  u16*   valueB = (u16*)  (ws + 1508864);     // 54,460,416 (MVPAD x 256 bf16)
  u16*   hB     = (u16*)  (ws + 1508864);     // 33,554,432 — reuses valueB (dead after msdeform)
  u16*   qpB    = (u16*)  (ws + 55969280);    // 8,388,608
  u16*   msout  = (u16*)  (ws + 55969280);    // 8,388,608 — reuses qpB (dead after comb GEMM)
  float* oa     = (float*)(ws + 64357888);    // 25,165,824 (dead after msdeform)
  float* xbuf   = (float*)(ws + 89523712);    // 16,777,216
  u16*   xnB    = (u16*)  (ws + 106300928);   // 8,388,608
  // total: 114,689,536 B

  float* out_x   = (float*)d_out;
  float* out_loc = (float*)d_out + (size_t)MQ * DIM_;

  // all weight transposes + combined bias, one kernel
  hipLaunchKernelGGL(prep_weights, dim3(2946), dim3(256), 0, stream,
                     Wv, Woff, Wattn, Wout, W1, W2, boff, battn,
                     WvT, WcombT, WoutT, W1T, W2T, bcomb);

  // qp = LN1(input)*g+b + pos   (bf16)
  hipLaunchKernelGGL((ln_k<true>), dim3(MQ / 4), dim3(256), 0, stream, input, pos, ln1_g, ln1_b, qpB);

  // value = source @ Wv + bv  (bf16 out; A fp32 converted in-staging)
  hipLaunchKernelGGL((gemm_k<1, true>), dim3(MVPAD / 128, 2), dim3(256), 0, stream,
                     (const void*)source, WvT, bv, (const float*)nullptr, (void*)valueB, 256, 256, MV);

  // [offsets|attn] raw = qp @ Wcomb + bcomb (f32, N=384)
  hipLaunchKernelGGL((gemm_k<0, false>), dim3(MQ / 128, 3), dim3(256), 0, stream,
                     (const void*)qpB, WcombT, bcomb, (const float*)nullptr, (void*)oa, 384, 256, MQ);

  // softmax + loc (writes output 1) + deformable sampling -> msout (bf16)
  hipLaunchKernelGGL(msdeform_k, dim3(MQ / 2), dim3(256), 0, stream,
                     valueB, oa, refpt, out_loc, msout);

  // x = input + msout @ Wout + bout (f32)
  hipLaunchKernelGGL((gemm_k<2, false>), dim3(MQ / 128, 2), dim3(256), 0, stream,
                     (const void*)msout, WoutT, bout, input, (void*)xbuf, 256, 256, MQ);

  // xn = LN2(x) (bf16)
  hipLaunchKernelGGL((ln_k<false>), dim3(MQ / 4), dim3(256), 0, stream, xbuf, (const float*)nullptr, ln2_g, ln2_b, xnB);

  // h = relu(xn @ W1 + b1) (bf16)
  hipLaunchKernelGGL((gemm_k<3, false>), dim3(MQ / 128, DFF / 128), dim3(256), 0, stream,
                     (const void*)xnB, W1T, b1, (const float*)nullptr, (void*)hB, DFF, 256, MQ);

  // out_x = x + h @ W2 + b2 (f32)
  hipLaunchKernelGGL((gemm_k<2, false>), dim3(MQ / 128, 2), dim3(256), 0, stream,
                     (const void*)hB, W2T, b2, xbuf, (void*)out_x, 256, 1024, MQ);
}

// Round 5
// 429.106 us; speedup vs baseline: 1.2235x; 1.0034x over previous
//
#include <hip/hip_runtime.h>
#include <hip/hip_bf16.h>
#include <cstdint>
#include <cstddef>

// ---------------- problem constants ----------------
#define B_    8
#define Q_    2048
#define DIM_  256
#define NH    8
#define HD    32
#define NL    4
#define NP    4
#define DFF   1024
#define LEN_IN_ 13294
#define MV    (B_*LEN_IN_)     // 106352
#define MVPAD 106368           // 831*128
#define MQ    (B_*Q_)          // 16384

typedef unsigned short u16;
typedef unsigned int   u32;
typedef __attribute__((ext_vector_type(8))) short short8;
typedef __attribute__((ext_vector_type(4))) float f32x4v;
typedef __attribute__((ext_vector_type(4))) unsigned short u16x4;

static __device__ __forceinline__ u16 f2bf(float f){
  union { float f; unsigned u; } x; x.f = f;
  unsigned r = x.u + 0x7fffu + ((x.u >> 16) & 1u);
  return (u16)(r >> 16);
}

#define GLDS(gp, lp) __builtin_amdgcn_global_load_lds( \
    (const __attribute__((address_space(1))) void*)(gp), \
    (__attribute__((address_space(3))) void*)(lp), 16, 0, 0)

// ---------------- generic bf16 MFMA GEMM, 2-phase double-buffered ----------------
// C[M][N] = A[M][K] @ Bt[N][K]^T + bias ; Bt bf16 row-major [N][K]; acc fp32.
// AF32: A is fp32 (reg-staged, converted during LDS write; rows >= Mstore read 0)
// EPI: 0 = f32 store (+bias); 1 = bf16 store (+bias);
//      2 = f32 store (+bias + residual); 3 = bf16 store (+bias + relu)
template<int EPI, bool AF32>
__global__ __launch_bounds__(256)
void gemm_k(const void* __restrict__ Ap, const u16* __restrict__ Bt,
            const float* __restrict__ bias, const float* __restrict__ res,
            void* __restrict__ outp, int N, int K, int Mstore)
{
  __shared__ u16 As[2][128*64];
  __shared__ u16 Bs[2][128*64];
  const int t = threadIdx.x;
  const int l = t & 63, wid = t >> 6;
  const int wm = wid >> 1, wn = wid & 1;
  const int m0 = blockIdx.x * 128, n0 = blockIdx.y * 128;

  f32x4v acc[4][4];
#pragma unroll
  for (int i = 0; i < 4; ++i)
#pragma unroll
    for (int j = 0; j < 4; ++j) acc[i][j] = 0.f;

  const int nkt = K >> 6;

  // ---- prologue: stage kt=0 into buffer 0
  {
    float4 pa[8];
#pragma unroll
    for (int i = 0; i < 4; ++i) {
      const int chunk = i * 256 + t;
      const int row = chunk >> 3;
      const int sc = (chunk & 7) ^ (row & 7);
      if (AF32) {
        const int gr = m0 + row;
        float4 z = {0.f, 0.f, 0.f, 0.f};
        pa[2*i] = z; pa[2*i+1] = z;
        if (gr < Mstore) {
          const float* ga = (const float*)Ap + (size_t)gr * K + sc * 8;
          pa[2*i]   = *reinterpret_cast<const float4*>(ga);
          pa[2*i+1] = *reinterpret_cast<const float4*>(ga + 4);
        }
      } else {
        const u16* ga = (const u16*)Ap + (size_t)(m0 + row) * K + sc * 8;
        GLDS(ga, As[0] + chunk * 8);
      }
      const u16* gb = Bt + (size_t)(n0 + row) * K + sc * 8;
      GLDS(gb, Bs[0] + chunk * 8);
    }
    asm volatile("s_waitcnt vmcnt(0)" ::: "memory");
    if (AF32) {
#pragma unroll
      for (int i = 0; i < 4; ++i) {
        const int chunk = i * 256 + t;
        short8 pk;
        pk[0]=(short)f2bf(pa[2*i].x);   pk[1]=(short)f2bf(pa[2*i].y);
        pk[2]=(short)f2bf(pa[2*i].z);   pk[3]=(short)f2bf(pa[2*i].w);
        pk[4]=(short)f2bf(pa[2*i+1].x); pk[5]=(short)f2bf(pa[2*i+1].y);
        pk[6]=(short)f2bf(pa[2*i+1].z); pk[7]=(short)f2bf(pa[2*i+1].w);
        *reinterpret_cast<short8*>(As[0] + chunk * 8) = pk;
      }
    }
    __syncthreads();
  }

  int cur = 0;
  for (int kt = 0; kt < nkt; ++kt) {
    const bool pf = (kt + 1 < nkt);
    float4 pa[8];
    // ---- issue next-tile stage (stays in flight under the MFMAs below)
    if (pf) {
      const int kn = (kt + 1) * 64;
#pragma unroll
      for (int i = 0; i < 4; ++i) {
        const int chunk = i * 256 + t;
        const int row = chunk >> 3;
        const int sc = (chunk & 7) ^ (row & 7);
        if (AF32) {
          const int gr = m0 + row;
          float4 z = {0.f, 0.f, 0.f, 0.f};
          pa[2*i] = z; pa[2*i+1] = z;
          if (gr < Mstore) {
            const float* ga = (const float*)Ap + (size_t)gr * K + kn + sc * 8;
            pa[2*i]   = *reinterpret_cast<const float4*>(ga);
            pa[2*i+1] = *reinterpret_cast<const float4*>(ga + 4);
          }
        } else {
          const u16* ga = (const u16*)Ap + (size_t)(m0 + row) * K + kn + sc * 8;
          GLDS(ga, As[cur ^ 1] + chunk * 8);
        }
        const u16* gb = Bt + (size_t)(n0 + row) * K + kn + sc * 8;
        GLDS(gb, Bs[cur ^ 1] + chunk * 8);
      }
    }
    // ---- compute on buffer cur
#pragma unroll
    for (int kk = 0; kk < 2; ++kk) {
      short8 af[4], bfr[4];
      const int lr  = l & 15;
      const int c   = kk * 4 + (l >> 4);
      const int swz = c ^ (lr & 7);
#pragma unroll
      for (int mi = 0; mi < 4; ++mi) {
        int r = wm * 64 + mi * 16 + lr;
        af[mi] = *reinterpret_cast<const short8*>(As[cur] + (r * 8 + swz) * 8);
      }
#pragma unroll
      for (int ni = 0; ni < 4; ++ni) {
        int r = wn * 64 + ni * 16 + lr;
        bfr[ni] = *reinterpret_cast<const short8*>(Bs[cur] + (r * 8 + swz) * 8);
      }
#pragma unroll
      for (int mi = 0; mi < 4; ++mi)
#pragma unroll
        for (int ni = 0; ni < 4; ++ni)
          acc[mi][ni] = __builtin_amdgcn_mfma_f32_16x16x32_bf16(af[mi], bfr[ni], acc[mi][ni], 0, 0, 0);
    }
    // ---- land the prefetch (write-late for AF32), then flip
    if (pf) {
      asm volatile("s_waitcnt vmcnt(0)" ::: "memory");
      if (AF32) {
#pragma unroll
        for (int i = 0; i < 4; ++i) {
          const int chunk = i * 256 + t;
          short8 pk;
          pk[0]=(short)f2bf(pa[2*i].x);   pk[1]=(short)f2bf(pa[2*i].y);
          pk[2]=(short)f2bf(pa[2*i].z);   pk[3]=(short)f2bf(pa[2*i].w);
          pk[4]=(short)f2bf(pa[2*i+1].x); pk[5]=(short)f2bf(pa[2*i+1].y);
          pk[6]=(short)f2bf(pa[2*i+1].z); pk[7]=(short)f2bf(pa[2*i+1].w);
          *reinterpret_cast<short8*>(As[cur ^ 1] + chunk * 8) = pk;
        }
      }
    }
    __syncthreads();
    cur ^= 1;
  }

  const int lr4 = l >> 4;
#pragma unroll
  for (int mi = 0; mi < 4; ++mi) {
    int rowb = m0 + wm * 64 + mi * 16 + lr4 * 4;
#pragma unroll
    for (int ni = 0; ni < 4; ++ni) {
      int col = n0 + wn * 64 + ni * 16 + (l & 15);
      float bb = bias[col];
#pragma unroll
      for (int v = 0; v < 4; ++v) {
        int r = rowb + v;
        if (r < Mstore) {
          float cv = acc[mi][ni][v] + bb;
          if (EPI == 2) cv += res[(size_t)r * N + col];
          if (EPI == 3) cv = fmaxf(cv, 0.f);
          if (EPI == 0 || EPI == 2) ((float*)outp)[(size_t)r * N + col] = cv;
          else                      ((u16*)outp)[(size_t)r * N + col] = f2bf(cv);
        }
      }
    }
  }
}

// ---------------- fused weight prep: all transposes + combined bias ----------------
__global__ void prep_weights(const float* __restrict__ Wv,   const float* __restrict__ Woff,
                             const float* __restrict__ Wattn,const float* __restrict__ Wout,
                             const float* __restrict__ W1,   const float* __restrict__ W2,
                             const float* __restrict__ boff, const float* __restrict__ battn,
                             u16* __restrict__ WvT, u16* __restrict__ WcombT,
                             u16* __restrict__ WoutT, u16* __restrict__ W1T,
                             u16* __restrict__ W2T, float* __restrict__ bcomb)
{
  const int gid = blockIdx.x * 256 + threadIdx.x;
  const int R0 = 65536, R1 = R0 + 98304, R2 = R1 + 65536, R3 = R2 + 262144,
            R4 = R3 + 262144, R5 = R4 + 384;
  if (gid < R0) {
    int n = gid >> 8, k = gid & 255;
    WvT[gid] = f2bf(Wv[(size_t)k * 256 + n]);
  } else if (gid < R1) {
    int lo = gid - R0, n = lo >> 8, k = lo & 255;
    float s = (n < 256) ? Woff[(size_t)k * 256 + n] : Wattn[(size_t)k * 128 + (n - 256)];
    WcombT[lo] = f2bf(s);
  } else if (gid < R2) {
    int lo = gid - R1, n = lo >> 8, k = lo & 255;
    WoutT[lo] = f2bf(Wout[(size_t)k * 256 + n]);
  } else if (gid < R3) {
    int lo = gid - R2, n = lo >> 8, k = lo & 255;
    W1T[lo] = f2bf(W1[(size_t)k * 1024 + n]);
  } else if (gid < R4) {
    int lo = gid - R3, n = lo >> 10, k = lo & 1023;
    W2T[lo] = f2bf(W2[(size_t)k * 256 + n]);
  } else if (gid < R5) {
    int lo = gid - R4;
    bcomb[lo] = (lo < 256) ? boff[lo] : battn[lo - 256];
  }
}

// ---------------- LayerNorm (warp per 256-float row) -> bf16 out ----------------
template<bool ADDPOS>
__global__ __launch_bounds__(256)
void ln_k(const float* __restrict__ x, const float* __restrict__ pos,
          const float* __restrict__ g, const float* __restrict__ b, u16* __restrict__ out)
{
  const int warp = threadIdx.x >> 6, l = threadIdx.x & 63;
  const int row = blockIdx.x * 4 + warp;
  const float4 xv = reinterpret_cast<const float4*>(x + (size_t)row * 256)[l];
  float s = xv.x + xv.y + xv.z + xv.w;
#pragma unroll
  for (int o = 32; o; o >>= 1) s += __shfl_xor(s, o);
  const float mean = s * (1.f / 256.f);
  const float d0 = xv.x - mean, d1 = xv.y - mean, d2 = xv.z - mean, d3 = xv.w - mean;
  float vs = d0 * d0 + d1 * d1 + d2 * d2 + d3 * d3;
#pragma unroll
  for (int o = 32; o; o >>= 1) vs += __shfl_xor(vs, o);
  const float rs = rsqrtf(vs * (1.f / 256.f) + 1e-5f);
  const float4 gv = reinterpret_cast<const float4*>(g)[l];
  const float4 bv = reinterpret_cast<const float4*>(b)[l];
  float o0 = d0 * rs * gv.x + bv.x;
  float o1 = d1 * rs * gv.y + bv.y;
  float o2 = d2 * rs * gv.z + bv.z;
  float o3 = d3 * rs * gv.w + bv.w;
  if (ADDPOS) {
    const float4 pv = reinterpret_cast<const float4*>(pos + (size_t)row * 256)[l];
    o0 += pv.x; o1 += pv.y; o2 += pv.z; o3 += pv.w;
  }
  u16x4 ov; ov.x = f2bf(o0); ov.y = f2bf(o1); ov.z = f2bf(o2); ov.w = f2bf(o3);
  reinterpret_cast<u16x4*>(out + (size_t)row * 256)[l] = ov;
}

// ---------------- fused softmax + loc + multiscale deformable sampling ----------------
__global__ __launch_bounds__(256)
void msdeform_k(const u16* __restrict__ value, const float* __restrict__ oa,
                const float* __restrict__ refpt, float* __restrict__ locout,
                u16* __restrict__ outp)
{
  const int t = threadIdx.x;
  const int rloc = t >> 7;              // row within block
  const int rem = t & 127;
  const int h = rem >> 4, p = rem & 15; // p = lane-in-group = point idx = dim-pair idx
  const int row = blockIdx.x * 2 + rloc;
  const int b = row >> 11;              // Q=2048
  const int lv = p >> 2;
  const float* orow = oa + (size_t)row * 384;

  // ---- softmax over the 16 points of (row,h)
  const float araw = orow[256 + h * 16 + p];
  float mx = araw;
#pragma unroll
  for (int o = 1; o < 16; o <<= 1) mx = fmaxf(mx, __shfl_xor(mx, o, 16));
  const float e = __expf(araw - mx);
  float se = e;
#pragma unroll
  for (int o = 1; o < 16; o <<= 1) se += __shfl_xor(se, o, 16);
  const float aw = e / se;

  // ---- loc = ref + off/normalizer  (write output 1)
  const float2 off = *reinterpret_cast<const float2*>(orow + h * 32 + p * 2);
  const float rn = (lv == 0) ? (1.f / 100.f) : (lv == 1) ? (1.f / 50.f)
                 : (lv == 2) ? (1.f / 25.f) : (1.f / 13.f);
  const float rx = refpt[(size_t)row * 8 + lv * 2 + 0];
  const float ry = refpt[(size_t)row * 8 + lv * 2 + 1];
  const float lx = rx + off.x * rn;
  const float ly = ry + off.y * rn;
  float2 lw; lw.x = lx; lw.y = ly;
  *reinterpret_cast<float2*>(locout + (((size_t)row * 8 + h) * 16 + p) * 2) = lw;

  // ---- this lane's point params
  const int Wl = (lv == 0) ? 100 : (lv == 1) ? 50 : (lv == 2) ? 25 : 13;
  const int st = (lv == 0) ? 0 : (lv == 1) ? 10000 : (lv == 2) ? 12500 : 13125;
  const float Wf = (float)Wl;
  const float xx = lx * Wf - 0.5f, yy = ly * Wf - 0.5f;
  const float xf = floorf(xx), yf = floorf(yy);
  const float wx = xx - xf, wy = yy - yf;
  const int x0 = (int)xf, y0 = (int)yf;
  const int xc0 = min(max(x0, 0), Wl - 1), xc1 = min(max(x0 + 1, 0), Wl - 1);
  const int yc0 = min(max(y0, 0), Wl - 1), yc1 = min(max(y0 + 1, 0), Wl - 1);
  const float vx0 = (x0 >= 0 && x0 < Wl) ? 1.f : 0.f;
  const float vx1 = (x0 + 1 >= 0 && x0 + 1 < Wl) ? 1.f : 0.f;
  const float vy0 = (y0 >= 0 && y0 < Wl) ? 1.f : 0.f;
  const float vy1 = (y0 + 1 >= 0 && y0 + 1 < Wl) ? 1.f : 0.f;
  const int o00 = st + yc0 * Wl + xc0, o01 = st + yc0 * Wl + xc1;
  const int o10 = st + yc1 * Wl + xc0, o11 = st + yc1 * Wl + xc1;
  const float w00 = aw * (1.f - wx) * (1.f - wy) * vx0 * vy0;
  const float w01 = aw * wx * (1.f - wy) * vx1 * vy0;
  const float w10 = aw * (1.f - wx) * wy * vx0 * vy1;
  const float w11 = aw * wx * wy * vx1 * vy1;

  const char* vbase = (const char*)value + (size_t)b * LEN_IN_ * 512 + (size_t)(h * 32 + p * 2) * 2;
  float a0 = 0.f, a1 = 0.f;
#pragma unroll
  for (int q = 0; q < 16; ++q) {
    const int   c00 = __shfl(o00, q, 16), c01 = __shfl(o01, q, 16);
    const int   c10 = __shfl(o10, q, 16), c11 = __shfl(o11, q, 16);
    const float u00 = __shfl(w00, q, 16), u01 = __shfl(w01, q, 16);
    const float u10 = __shfl(w10, q, 16), u11 = __shfl(w11, q, 16);
    const u32 g00 = *reinterpret_cast<const u32*>(vbase + (size_t)c00 * 512);
    const u32 g01 = *reinterpret_cast<const u32*>(vbase + (size_t)c01 * 512);
    const u32 g10 = *reinterpret_cast<const u32*>(vbase + (size_t)c10 * 512);
    const u32 g11 = *reinterpret_cast<const u32*>(vbase + (size_t)c11 * 512);
    union { u32 u; float f; } lo, hi;
    lo.u = g00 << 16; hi.u = g00 & 0xffff0000u; a0 += u00 * lo.f; a1 += u00 * hi.f;
    lo.u = g01 << 16; hi.u = g01 & 0xffff0000u; a0 += u01 * lo.f; a1 += u01 * hi.f;
    lo.u = g10 << 16; hi.u = g10 & 0xffff0000u; a0 += u10 * lo.f; a1 += u10 * hi.f;
    lo.u = g11 << 16; hi.u = g11 & 0xffff0000u; a0 += u11 * lo.f; a1 += u11 * hi.f;
  }
  const u32 res = ((u32)f2bf(a1) << 16) | (u32)f2bf(a0);
  reinterpret_cast<u32*>(outp)[(size_t)row * 128 + h * 16 + p] = res;
}

// ---------------- launch ----------------
extern "C" void kernel_launch(void* const* d_in, const int* in_sizes, int n_in,
                              void* d_out, int out_size, void* d_ws, size_t ws_size,
                              hipStream_t stream)
{
  (void)in_sizes; (void)n_in; (void)out_size; (void)ws_size;
  const float* input  = (const float*)d_in[0];
  const float* pos    = (const float*)d_in[1];
  const float* refpt  = (const float*)d_in[2];
  const float* source = (const float*)d_in[3];
  const float* ln1_g  = (const float*)d_in[7];
  const float* ln1_b  = (const float*)d_in[8];
  const float* ln2_g  = (const float*)d_in[9];
  const float* ln2_b  = (const float*)d_in[10];
  const float* Wv     = (const float*)d_in[11];
  const float* bv     = (const float*)d_in[12];
  const float* Woff   = (const float*)d_in[13];
  const float* boff   = (const float*)d_in[14];
  const float* Wattn  = (const float*)d_in[15];
  const float* battn  = (const float*)d_in[16];
  const float* Wout   = (const float*)d_in[17];
  const float* bout   = (const float*)d_in[18];
  const float* W1     = (const float*)d_in[19];
  const float* b1     = (const float*)d_in[20];
  const float* W2     = (const float*)d_in[21];
  const float* b2     = (const float*)d_in[22];

  char* ws = (char*)d_ws;
  u16*   WvT    = (u16*)  (ws + 0);           // 131072
  u16*   WcombT = (u16*)  (ws + 131072);      // 196608 ([384][256])
  u16*   WoutT  = (u16*)  (ws + 327680);      // 131072
  u16*   W1T    = (u16*)  (ws + 458752);      // 524288
  u16*   W2T    = (u16*)  (ws + 983040);      // 524288
  float* bcomb  = (float*)(ws + 1507328);     // 1536
  u16*   valueB = (u16*)  (ws + 1508864);     // 54,460,416 (MVPAD x 256 bf16)
  u16*   hB     = (u16*)  (ws + 1508864);     // 33,554,432 — reuses valueB (dead after msdeform)
  u16*   qpB    = (u16*)  (ws + 55969280);    // 8,388,608
  u16*   msout  = (u16*)  (ws + 55969280);    // 8,388,608 — reuses qpB (dead after comb GEMM)
  float* oa     = (float*)(ws + 64357888);    // 25,165,824 (dead after msdeform)
  float* xbuf   = (float*)(ws + 89523712);    // 16,777,216
  u16*   xnB    = (u16*)  (ws + 106300928);   // 8,388,608
  // total: 114,689,536 B

  float* out_x   = (float*)d_out;
  float* out_loc = (float*)d_out + (size_t)MQ * DIM_;

  // all weight transposes + combined bias, one kernel
  hipLaunchKernelGGL(prep_weights, dim3(2946), dim3(256), 0, stream,
                     Wv, Woff, Wattn, Wout, W1, W2, boff, battn,
                     WvT, WcombT, WoutT, W1T, W2T, bcomb);

  // qp = LN1(input)*g+b + pos   (bf16)
  hipLaunchKernelGGL((ln_k<true>), dim3(MQ / 4), dim3(256), 0, stream, input, pos, ln1_g, ln1_b, qpB);

  // value = source @ Wv + bv  (bf16 out; A fp32 converted in-staging)
  hipLaunchKernelGGL((gemm_k<1, true>), dim3(MVPAD / 128, 2), dim3(256), 0, stream,
                     (const void*)source, WvT, bv, (const float*)nullptr, (void*)valueB, 256, 256, MV);

  // [offsets|attn] raw = qp @ Wcomb + bcomb (f32, N=384)
  hipLaunchKernelGGL((gemm_k<0, false>), dim3(MQ / 128, 3), dim3(256), 0, stream,
                     (const void*)qpB, WcombT, bcomb, (const float*)nullptr, (void*)oa, 384, 256, MQ);

  // softmax + loc (writes output 1) + deformable sampling -> msout (bf16)
  hipLaunchKernelGGL(msdeform_k, dim3(MQ / 2), dim3(256), 0, stream,
                     valueB, oa, refpt, out_loc, msout);

  // x = input + msout @ Wout + bout (f32)
  hipLaunchKernelGGL((gemm_k<2, false>), dim3(MQ / 128, 2), dim3(256), 0, stream,
                     (const void*)msout, WoutT, bout, input, (void*)xbuf, 256, 256, MQ);

  // xn = LN2(x) (bf16)
  hipLaunchKernelGGL((ln_k<false>), dim3(MQ / 4), dim3(256), 0, stream, xbuf, (const float*)nullptr, ln2_g, ln2_b, xnB);

  // h = relu(xn @ W1 + b1) (bf16)
  hipLaunchKernelGGL((gemm_k<3, false>), dim3(MQ / 128, DFF / 128), dim3(256), 0, stream,
                     (const void*)xnB, W1T, b1, (const float*)nullptr, (void*)hB, DFF, 256, MQ);

  // out_x = x + h @ W2 + b2 (f32)
  hipLaunchKernelGGL((gemm_k<2, false>), dim3(MQ / 128, 2), dim3(256), 0, stream,
                     (const void*)hB, W2T, b2, xbuf, (void*)out_x, 256, 1024, MQ);
}

// Round 7
// 413.682 us; speedup vs baseline: 1.2691x; 1.0373x over previous
//
#include <hip/hip_runtime.h>
#include <hip/hip_bf16.h>
#include <cstdint>
#include <cstddef>

// ---------------- problem constants ----------------
#define B_    8
#define Q_    2048
#define DIM_  256
#define NH    8
#define HD    32
#define NL    4
#define NP    4
#define DFF   1024
#define LEN_IN_ 13294
#define MV    (B_*LEN_IN_)     // 106352
#define MVPAD 106368           // 831*128
#define MQ    (B_*Q_)          // 16384

typedef unsigned short u16;
typedef unsigned int   u32;
typedef __attribute__((ext_vector_type(8))) short short8;
typedef __attribute__((ext_vector_type(4))) float f32x4v;
typedef __attribute__((ext_vector_type(4))) unsigned short u16x4;

static __device__ __forceinline__ u16 f2bf(float f){
  union { float f; unsigned u; } x; x.f = f;
  unsigned r = x.u + 0x7fffu + ((x.u >> 16) & 1u);
  return (u16)(r >> 16);
}

#define GLDS(gp, lp) __builtin_amdgcn_global_load_lds( \
    (const __attribute__((address_space(1))) void*)(gp), \
    (__attribute__((address_space(3))) void*)(lp), 16, 0, 0)

// ---------------- bf16 MFMA GEMM: 8 waves / 128x128 tile, 2-phase dbuf ----------------
// Wave-tile 64x32 -> acc[4][2] = 32 AGPRs/thread (occupancy: 2 blocks x 8 waves/CU).
// C[M][N] = A[M][K] @ Bt[N][K]^T + bias ; Bt bf16 row-major [N][K]; acc fp32.
// AF32: A is fp32 (reg-staged, converted during LDS write; rows >= Mstore read 0)
// EPI: 0 = f32 store (+bias); 1 = bf16 store (+bias);
//      2 = f32 store (+bias + residual); 3 = bf16 store (+bias + relu)
template<int EPI, bool AF32>
__global__ __launch_bounds__(512, 4)
void gemm_k(const void* __restrict__ Ap, const u16* __restrict__ Bt,
            const float* __restrict__ bias, const float* __restrict__ res,
            void* __restrict__ outp, int N, int K, int Mstore)
{
  __shared__ u16 As[2][128*64];
  __shared__ u16 Bs[2][128*64];
  const int t = threadIdx.x;
  const int l = t & 63, wid = t >> 6;       // 8 waves
  const int wm = wid >> 2, wn = wid & 3;    // 2 x 4 wave grid
  const int m0 = blockIdx.x * 128, n0 = blockIdx.y * 128;

  f32x4v acc[4][2];
#pragma unroll
  for (int i = 0; i < 4; ++i)
#pragma unroll
    for (int j = 0; j < 2; ++j) acc[i][j] = 0.f;

  const int nkt = K >> 6;

  // ---- prologue: stage kt=0 into buffer 0
  {
    float4 pa[4];
#pragma unroll
    for (int i = 0; i < 2; ++i) {
      const int chunk = i * 512 + t;        // 0..1023 16B-chunks
      const int row = chunk >> 3;           // 8 chunks per 64-col row
      const int sc = (chunk & 7) ^ (row & 7);
      if (AF32) {
        const int gr = m0 + row;
        float4 z = {0.f, 0.f, 0.f, 0.f};
        pa[2*i] = z; pa[2*i+1] = z;
        if (gr < Mstore) {
          const float* ga = (const float*)Ap + (size_t)gr * K + sc * 8;
          pa[2*i]   = *reinterpret_cast<const float4*>(ga);
          pa[2*i+1] = *reinterpret_cast<const float4*>(ga + 4);
        }
      } else {
        const u16* ga = (const u16*)Ap + (size_t)(m0 + row) * K + sc * 8;
        GLDS(ga, As[0] + chunk * 8);
      }
      const u16* gb = Bt + (size_t)(n0 + row) * K + sc * 8;
      GLDS(gb, Bs[0] + chunk * 8);
    }
    if (AF32) {
#pragma unroll
      for (int i = 0; i < 2; ++i) {
        const int chunk = i * 512 + t;
        short8 pk;
        pk[0]=(short)f2bf(pa[2*i].x);   pk[1]=(short)f2bf(pa[2*i].y);
        pk[2]=(short)f2bf(pa[2*i].z);   pk[3]=(short)f2bf(pa[2*i].w);
        pk[4]=(short)f2bf(pa[2*i+1].x); pk[5]=(short)f2bf(pa[2*i+1].y);
        pk[6]=(short)f2bf(pa[2*i+1].z); pk[7]=(short)f2bf(pa[2*i+1].w);
        *reinterpret_cast<short8*>(As[0] + chunk * 8) = pk;
      }
    }
    __syncthreads();
  }

  int cur = 0;
  for (int kt = 0; kt < nkt; ++kt) {
    const bool pf = (kt + 1 < nkt);
    float4 pa[4];
    // ---- issue next-tile stage early (in flight under the MFMAs below)
    if (pf) {
      const int kn = (kt + 1) * 64;
#pragma unroll
      for (int i = 0; i < 2; ++i) {
        const int chunk = i * 512 + t;
        const int row = chunk >> 3;
        const int sc = (chunk & 7) ^ (row & 7);
        if (AF32) {
          const int gr = m0 + row;
          float4 z = {0.f, 0.f, 0.f, 0.f};
          pa[2*i] = z; pa[2*i+1] = z;
          if (gr < Mstore) {
            const float* ga = (const float*)Ap + (size_t)gr * K + kn + sc * 8;
            pa[2*i]   = *reinterpret_cast<const float4*>(ga);
            pa[2*i+1] = *reinterpret_cast<const float4*>(ga + 4);
          }
        } else {
          const u16* ga = (const u16*)Ap + (size_t)(m0 + row) * K + kn + sc * 8;
          GLDS(ga, As[cur ^ 1] + chunk * 8);
        }
        const u16* gb = Bt + (size_t)(n0 + row) * K + kn + sc * 8;
        GLDS(gb, Bs[cur ^ 1] + chunk * 8);
      }
    }
    // ---- compute on buffer cur
#pragma unroll
    for (int kk = 0; kk < 2; ++kk) {
      short8 af[4], bfr[2];
      const int lr  = l & 15;
      const int c   = kk * 4 + (l >> 4);
      const int swz = c ^ (lr & 7);
#pragma unroll
      for (int mi = 0; mi < 4; ++mi) {
        int r = wm * 64 + mi * 16 + lr;
        af[mi] = *reinterpret_cast<const short8*>(As[cur] + (r * 8 + swz) * 8);
      }
#pragma unroll
      for (int ni = 0; ni < 2; ++ni) {
        int r = wn * 32 + ni * 16 + lr;
        bfr[ni] = *reinterpret_cast<const short8*>(Bs[cur] + (r * 8 + swz) * 8);
      }
#pragma unroll
      for (int mi = 0; mi < 4; ++mi)
#pragma unroll
        for (int ni = 0; ni < 2; ++ni)
          acc[mi][ni] = __builtin_amdgcn_mfma_f32_16x16x32_bf16(af[mi], bfr[ni], acc[mi][ni], 0, 0, 0);
    }
    // ---- land the prefetch (write-late for AF32), then flip
    if (pf && AF32) {
#pragma unroll
      for (int i = 0; i < 2; ++i) {
        const int chunk = i * 512 + t;
        short8 pk;
        pk[0]=(short)f2bf(pa[2*i].x);   pk[1]=(short)f2bf(pa[2*i].y);
        pk[2]=(short)f2bf(pa[2*i].z);   pk[3]=(short)f2bf(pa[2*i].w);
        pk[4]=(short)f2bf(pa[2*i+1].x); pk[5]=(short)f2bf(pa[2*i+1].y);
        pk[6]=(short)f2bf(pa[2*i+1].z); pk[7]=(short)f2bf(pa[2*i+1].w);
        *reinterpret_cast<short8*>(As[cur ^ 1] + chunk * 8) = pk;
      }
    }
    __syncthreads();   // compiler emits full vmcnt/lgkmcnt drain before barrier
    cur ^= 1;
  }

  const int lr4 = l >> 4;
#pragma unroll
  for (int mi = 0; mi < 4; ++mi) {
    int rowb = m0 + wm * 64 + mi * 16 + lr4 * 4;
#pragma unroll
    for (int ni = 0; ni < 2; ++ni) {
      int col = n0 + wn * 32 + ni * 16 + (l & 15);
      float bb = bias[col];
#pragma unroll
      for (int v = 0; v < 4; ++v) {
        int r = rowb + v;
        if (r < Mstore) {
          float cv = acc[mi][ni][v] + bb;
          if (EPI == 2) cv += res[(size_t)r * N + col];
          if (EPI == 3) cv = fmaxf(cv, 0.f);
          if (EPI == 0 || EPI == 2) ((float*)outp)[(size_t)r * N + col] = cv;
          else                      ((u16*)outp)[(size_t)r * N + col] = f2bf(cv);
        }
      }
    }
  }
}

// ---------------- fused weight prep: all transposes + combined bias ----------------
__global__ void prep_weights(const float* __restrict__ Wv,   const float* __restrict__ Woff,
                             const float* __restrict__ Wattn,const float* __restrict__ Wout,
                             const float* __restrict__ W1,   const float* __restrict__ W2,
                             const float* __restrict__ boff, const float* __restrict__ battn,
                             u16* __restrict__ WvT, u16* __restrict__ WcombT,
                             u16* __restrict__ WoutT, u16* __restrict__ W1T,
                             u16* __restrict__ W2T, float* __restrict__ bcomb)
{
  const int gid = blockIdx.x * 256 + threadIdx.x;
  const int R0 = 65536, R1 = R0 + 98304, R2 = R1 + 65536, R3 = R2 + 262144,
            R4 = R3 + 262144, R5 = R4 + 384;
  if (gid < R0) {
    int n = gid >> 8, k = gid & 255;
    WvT[gid] = f2bf(Wv[(size_t)k * 256 + n]);
  } else if (gid < R1) {
    int lo = gid - R0, n = lo >> 8, k = lo & 255;
    float s = (n < 256) ? Woff[(size_t)k * 256 + n] : Wattn[(size_t)k * 128 + (n - 256)];
    WcombT[lo] = f2bf(s);
  } else if (gid < R2) {
    int lo = gid - R1, n = lo >> 8, k = lo & 255;
    WoutT[lo] = f2bf(Wout[(size_t)k * 256 + n]);
  } else if (gid < R3) {
    int lo = gid - R2, n = lo >> 8, k = lo & 255;
    W1T[lo] = f2bf(W1[(size_t)k * 1024 + n]);
  } else if (gid < R4) {
    int lo = gid - R3, n = lo >> 10, k = lo & 1023;
    W2T[lo] = f2bf(W2[(size_t)k * 256 + n]);
  } else if (gid < R5) {
    int lo = gid - R4;
    bcomb[lo] = (lo < 256) ? boff[lo] : battn[lo - 256];
  }
}

// ---------------- LayerNorm (warp per 256-float row) -> bf16 out ----------------
template<bool ADDPOS>
__global__ __launch_bounds__(256)
void ln_k(const float* __restrict__ x, const float* __restrict__ pos,
          const float* __restrict__ g, const float* __restrict__ b, u16* __restrict__ out)
{
  const int warp = threadIdx.x >> 6, l = threadIdx.x & 63;
  const int row = blockIdx.x * 4 + warp;
  const float4 xv = reinterpret_cast<const float4*>(x + (size_t)row * 256)[l];
  float s = xv.x + xv.y + xv.z + xv.w;
#pragma unroll
  for (int o = 32; o; o >>= 1) s += __shfl_xor(s, o);
  const float mean = s * (1.f / 256.f);
  const float d0 = xv.x - mean, d1 = xv.y - mean, d2 = xv.z - mean, d3 = xv.w - mean;
  float vs = d0 * d0 + d1 * d1 + d2 * d2 + d3 * d3;
#pragma unroll
  for (int o = 32; o; o >>= 1) vs += __shfl_xor(vs, o);
  const float rs = rsqrtf(vs * (1.f / 256.f) + 1e-5f);
  const float4 gv = reinterpret_cast<const float4*>(g)[l];
  const float4 bv = reinterpret_cast<const float4*>(b)[l];
  float o0 = d0 * rs * gv.x + bv.x;
  float o1 = d1 * rs * gv.y + bv.y;
  float o2 = d2 * rs * gv.z + bv.z;
  float o3 = d3 * rs * gv.w + bv.w;
  if (ADDPOS) {
    const float4 pv = reinterpret_cast<const float4*>(pos + (size_t)row * 256)[l];
    o0 += pv.x; o1 += pv.y; o2 += pv.z; o3 += pv.w;
  }
  u16x4 ov; ov.x = f2bf(o0); ov.y = f2bf(o1); ov.z = f2bf(o2); ov.w = f2bf(o3);
  reinterpret_cast<u16x4*>(out + (size_t)row * 256)[l] = ov;
}

// ---------------- fused softmax + loc + multiscale deformable sampling ----------------
__global__ __launch_bounds__(256)
void msdeform_k(const u16* __restrict__ value, const float* __restrict__ oa,
                const float* __restrict__ refpt, float* __restrict__ locout,
                u16* __restrict__ outp)
{
  const int t = threadIdx.x;
  const int rloc = t >> 7;              // row within block
  const int rem = t & 127;
  const int h = rem >> 4, p = rem & 15; // p = lane-in-group = point idx = dim-pair idx
  const int row = blockIdx.x * 2 + rloc;
  const int b = row >> 11;              // Q=2048
  const int lv = p >> 2;
  const float* orow = oa + (size_t)row * 384;

  // ---- softmax over the 16 points of (row,h)
  const float araw = orow[256 + h * 16 + p];
  float mx = araw;
#pragma unroll
  for (int o = 1; o < 16; o <<= 1) mx = fmaxf(mx, __shfl_xor(mx, o, 16));
  const float e = __expf(araw - mx);
  float se = e;
#pragma unroll
  for (int o = 1; o < 16; o <<= 1) se += __shfl_xor(se, o, 16);
  const float aw = e / se;

  // ---- loc = ref + off/normalizer  (write output 1)
  const float2 off = *reinterpret_cast<const float2*>(orow + h * 32 + p * 2);
  const float rn = (lv == 0) ? (1.f / 100.f) : (lv == 1) ? (1.f / 50.f)
                 : (lv == 2) ? (1.f / 25.f) : (1.f / 13.f);
  const float rx = refpt[(size_t)row * 8 + lv * 2 + 0];
  const float ry = refpt[(size_t)row * 8 + lv * 2 + 1];
  const float lx = rx + off.x * rn;
  const float ly = ry + off.y * rn;
  float2 lw; lw.x = lx; lw.y = ly;
  *reinterpret_cast<float2*>(locout + (((size_t)row * 8 + h) * 16 + p) * 2) = lw;

  // ---- this lane's point params
  const int Wl = (lv == 0) ? 100 : (lv == 1) ? 50 : (lv == 2) ? 25 : 13;
  const int st = (lv == 0) ? 0 : (lv == 1) ? 10000 : (lv == 2) ? 12500 : 13125;
  const float Wf = (float)Wl;
  const float xx = lx * Wf - 0.5f, yy = ly * Wf - 0.5f;
  const float xf = floorf(xx), yf = floorf(yy);
  const float wx = xx - xf, wy = yy - yf;
  const int x0 = (int)xf, y0 = (int)yf;
  const int xc0 = min(max(x0, 0), Wl - 1), xc1 = min(max(x0 + 1, 0), Wl - 1);
  const int yc0 = min(max(y0, 0), Wl - 1), yc1 = min(max(y0 + 1, 0), Wl - 1);
  const float vx0 = (x0 >= 0 && x0 < Wl) ? 1.f : 0.f;
  const float vx1 = (x0 + 1 >= 0 && x0 + 1 < Wl) ? 1.f : 0.f;
  const float vy0 = (y0 >= 0 && y0 < Wl) ? 1.f : 0.f;
  const float vy1 = (y0 + 1 >= 0 && y0 + 1 < Wl) ? 1.f : 0.f;
  const int o00 = st + yc0 * Wl + xc0, o01 = st + yc0 * Wl + xc1;
  const int o10 = st + yc1 * Wl + xc0, o11 = st + yc1 * Wl + xc1;
  const float w00 = aw * (1.f - wx) * (1.f - wy) * vx0 * vy0;
  const float w01 = aw * wx * (1.f - wy) * vx1 * vy0;
  const float w10 = aw * (1.f - wx) * wy * vx0 * vy1;
  const float w11 = aw * wx * wy * vx1 * vy1;

  const char* vbase = (const char*)value + (size_t)b * LEN_IN_ * 512 + (size_t)(h * 32 + p * 2) * 2;
  float a0 = 0.f, a1 = 0.f;
#pragma unroll
  for (int q = 0; q < 16; ++q) {
    const int   c00 = __shfl(o00, q, 16), c01 = __shfl(o01, q, 16);
    const int   c10 = __shfl(o10, q, 16), c11 = __shfl(o11, q, 16);
    const float u00 = __shfl(w00, q, 16), u01 = __shfl(w01, q, 16);
    const float u10 = __shfl(w10, q, 16), u11 = __shfl(w11, q, 16);
    const u32 g00 = *reinterpret_cast<const u32*>(vbase + (size_t)c00 * 512);
    const u32 g01 = *reinterpret_cast<const u32*>(vbase + (size_t)c01 * 512);
    const u32 g10 = *reinterpret_cast<const u32*>(vbase + (size_t)c10 * 512);
    const u32 g11 = *reinterpret_cast<const u32*>(vbase + (size_t)c11 * 512);
    union { u32 u; float f; } lo, hi;
    lo.u = g00 << 16; hi.u = g00 & 0xffff0000u; a0 += u00 * lo.f; a1 += u00 * hi.f;
    lo.u = g01 << 16; hi.u = g01 & 0xffff0000u; a0 += u01 * lo.f; a1 += u01 * hi.f;
    lo.u = g10 << 16; hi.u = g10 & 0xffff0000u; a0 += u10 * lo.f; a1 += u10 * hi.f;
    lo.u = g11 << 16; hi.u = g11 & 0xffff0000u; a0 += u11 * lo.f; a1 += u11 * hi.f;
  }
  const u32 res = ((u32)f2bf(a1) << 16) | (u32)f2bf(a0);
  reinterpret_cast<u32*>(outp)[(size_t)row * 128 + h * 16 + p] = res;
}

// ---------------- launch ----------------
extern "C" void kernel_launch(void* const* d_in, const int* in_sizes, int n_in,
                              void* d_out, int out_size, void* d_ws, size_t ws_size,
                              hipStream_t stream)
{
  (void)in_sizes; (void)n_in; (void)out_size; (void)ws_size;
  const float* input  = (const float*)d_in[0];
  const float* pos    = (const float*)d_in[1];
  const float* refpt  = (const float*)d_in[2];
  const float* source = (const float*)d_in[3];
  const float* ln1_g  = (const float*)d_in[7];
  const float* ln1_b  = (const float*)d_in[8];
  const float* ln2_g  = (const float*)d_in[9];
  const float* ln2_b  = (const float*)d_in[10];
  const float* Wv     = (const float*)d_in[11];
  const float* bv     = (const float*)d_in[12];
  const float* Woff   = (const float*)d_in[13];
  const float* boff   = (const float*)d_in[14];
  const float* Wattn  = (const float*)d_in[15];
  const float* battn  = (const float*)d_in[16];
  const float* Wout   = (const float*)d_in[17];
  const float* bout   = (const float*)d_in[18];
  const float* W1     = (const float*)d_in[19];
  const float* b1     = (const float*)d_in[20];
  const float* W2     = (const float*)d_in[21];
  const float* b2     = (const float*)d_in[22];

  char* ws = (char*)d_ws;
  u16*   WvT    = (u16*)  (ws + 0);           // 131072
  u16*   WcombT = (u16*)  (ws + 131072);      // 196608 ([384][256])
  u16*   WoutT  = (u16*)  (ws + 327680);      // 131072
  u16*   W1T    = (u16*)  (ws + 458752);      // 524288
  u16*   W2T    = (u16*)  (ws + 983040);      // 524288
  float* bcomb  = (float*)(ws + 1507328);     // 1536
  u16*   valueB = (u16*)  (ws + 1508864);     // 54,460,416 (MVPAD x 256 bf16)
  u16*   hB     = (u16*)  (ws + 1508864);     // 33,554,432 — reuses valueB (dead after msdeform)
  u16*   qpB    = (u16*)  (ws + 55969280);    // 8,388,608
  u16*   msout  = (u16*)  (ws + 55969280);    // 8,388,608 — reuses qpB (dead after comb GEMM)
  float* oa     = (float*)(ws + 64357888);    // 25,165,824 (dead after msdeform)
  float* xbuf   = (float*)(ws + 89523712);    // 16,777,216
  u16*   xnB    = (u16*)  (ws + 106300928);   // 8,388,608
  // total: 114,689,536 B

  float* out_x   = (float*)d_out;
  float* out_loc = (float*)d_out + (size_t)MQ * DIM_;

  // all weight transposes + combined bias, one kernel
  hipLaunchKernelGGL(prep_weights, dim3(2946), dim3(256), 0, stream,
                     Wv, Woff, Wattn, Wout, W1, W2, boff, battn,
                     WvT, WcombT, WoutT, W1T, W2T, bcomb);

  // qp = LN1(input)*g+b + pos   (bf16)
  hipLaunchKernelGGL((ln_k<true>), dim3(MQ / 4), dim3(256), 0, stream, input, pos, ln1_g, ln1_b, qpB);

  // value = source @ Wv + bv  (bf16 out; A fp32 converted in-staging)
  hipLaunchKernelGGL((gemm_k<1, true>), dim3(MVPAD / 128, 2), dim3(512), 0, stream,
                     (const void*)source, WvT, bv, (const float*)nullptr, (void*)valueB, 256, 256, MV);

  // [offsets|attn] raw = qp @ Wcomb + bcomb (f32, N=384)
  hipLaunchKernelGGL((gemm_k<0, false>), dim3(MQ / 128, 3), dim3(512), 0, stream,
                     (const void*)qpB, WcombT, bcomb, (const float*)nullptr, (void*)oa, 384, 256, MQ);

  // softmax + loc (writes output 1) + deformable sampling -> msout (bf16)
  hipLaunchKernelGGL(msdeform_k, dim3(MQ / 2), dim3(256), 0, stream,
                     valueB, oa, refpt, out_loc, msout);

  // x = input + msout @ Wout + bout (f32)
  hipLaunchKernelGGL((gemm_k<2, false>), dim3(MQ / 128, 2), dim3(512), 0, stream,
                     (const void*)msout, WoutT, bout, input, (void*)xbuf, 256, 256, MQ);

  // xn = LN2(x) (bf16)
  hipLaunchKernelGGL((ln_k<false>), dim3(MQ / 4), dim3(256), 0, stream, xbuf, (const float*)nullptr, ln2_g, ln2_b, xnB);

  // h = relu(xn @ W1 + b1) (bf16)
  hipLaunchKernelGGL((gemm_k<3, false>), dim3(MQ / 128, DFF / 128), dim3(512), 0, stream,
                     (const void*)xnB, W1T, b1, (const float*)nullptr, (void*)hB, DFF, 256, MQ);

  // out_x = x + h @ W2 + b2 (f32)
  hipLaunchKernelGGL((gemm_k<2, false>), dim3(MQ / 128, 2), dim3(512), 0, stream,
                     (const void*)hB, W2T, b2, xbuf, (void*)out_x, 256, 1024, MQ);
}